// Round 11
// baseline (531.003 us; speedup 1.0000x reference)
//
#include <hip/hip_runtime.h>
#include <cmath>

namespace {
constexpr int BPTS  = 16384;
constexpr int NPOSE = 32;
constexpr int KV    = 8;
constexpr int HD    = 256;
constexpr int TM    = 128;      // points per block (mlp)
constexpr float TAU = 0.015f;   // argmin ambiguity threshold (~3x max 2-term err)

constexpr size_t OFF_XLOCAL = 0;
constexpr size_t OFF_XLA    = (size_t)BPTS * 3;
constexpr size_t OFF_MINENC = OFF_XLA + (size_t)NPOSE * BPTS * 3;
constexpr size_t OFF_POSEQ  = OFF_MINENC + (size_t)BPTS * NPOSE;
constexpr size_t OFF_CLASS  = OFF_POSEQ + (size_t)BPTS * 16;
constexpr size_t OFF_PRED   = OFF_CLASS + (size_t)BPTS;
constexpr size_t OFF_VECQ   = OFF_PRED + (size_t)BPTS * NPOSE;

// workspace: f16 weight fragments (hi/lo), then reverify structures
constexpr size_t WS_W0H = 0;         // f16 element offsets
constexpr size_t WS_W0L = 16384;
constexpr size_t WS_W1H = 32768;
constexpr size_t WS_W1L = 98304;
constexpr size_t WS_W2H = 163840;
constexpr size_t WS_W2L = 229376;
constexpr size_t WB_END   = 589824;              // bytes
constexpr size_t CNT_B    = WB_END;
constexpr size_t PAIRS_B  = WB_END + 1024;
constexpr int    PAIR_CAP = 65536;
constexpr size_t EXACT_B  = PAIRS_B + (size_t)PAIR_CAP * 8;

// LDS layout (mlp): h buffer 64KB | feat 10KB | predp 4KB = 78KB -> 2 blocks/CU
constexpr int LDS_FEAT  = 65536;
constexpr int LDS_PREDP = 65536 + 10240;
constexpr int LDS_TOTAL = 65536 + 10240 + 4096;
}

typedef _Float16 f16;
typedef __attribute__((ext_vector_type(4))) _Float16 f16x4;
typedef __attribute__((ext_vector_type(8))) _Float16 f16x8;
typedef __attribute__((ext_vector_type(4))) float    f32x4;

#define MFMA16(a, b, c) __builtin_amdgcn_mfma_f32_16x16x32_f16((a), (b), (c), 0, 0, 0)

// ---- merged weight prep (+ cnt zero): split fp32 W[k][ch] into hi/lo f16 frags.
// idx = ((cht*KC + kc)*64 + lane)*8 + e -> W[k=kc*32+(lane>>4)*8+e][ch=cht*16+(lane&15)]
__global__ __launch_bounds__(256)
void prep_all(const float* __restrict__ w0, const float* __restrict__ w1,
              const float* __restrict__ w2, f16* __restrict__ wf, int* __restrict__ cnt)
{
    const int bid = blockIdx.x, tid = threadIdx.x;
    if (bid == 0 && tid == 0) *cnt = 0;
    if (bid < 64) {                       // w0: KC=2, 16384 frags
        int i = bid * 256 + tid;
        int e  = i & 7;
        int l  = (i >> 3) & 63;
        int kc = (i >> 9) & 1;
        int nt = i >> 10;
        int k   = kc * 32 + ((l >> 4) << 3) + e;
        int col = nt * 16 + (l & 15);
        float v = (k < 39) ? w0[k * HD + col] : 0.f;
        f16 hi = (f16)v;
        wf[WS_W0H + i] = hi;
        wf[WS_W0L + i] = (f16)(v - (float)hi);
    } else {                              // w1/w2: KC=8, 65536 frags each
        const bool is1 = bid < 320;
        const float* w = is1 ? w1 : w2;
        int i = (bid - (is1 ? 64 : 320)) * 256 + tid;
        int e  = i & 7;
        int l  = (i >> 3) & 63;
        int kc = (i >> 9) & 7;
        int nt = i >> 12;
        int k   = kc * 32 + ((l >> 4) << 3) + e;
        int col = nt * 16 + (l & 15);
        float v = w[k * HD + col];
        f16 hi = (f16)v;
        wf[(is1 ? WS_W1H : WS_W2H) + i] = hi;
        wf[(is1 ? WS_W1L : WS_W2L) + i] = (f16)(v - (float)hi);
    }
}

// swizzled byte address in the 512B full-width row: p 0..127, cbyte 0..511
__device__ __forceinline__ int bswz(int p, int cbyte) {
    return p * 512 + (cbyte ^ ((p & 15) << 4));
}

// (512,4): 128-reg total budget. acc is 32 AGPR (point-half schedule) + ~55 arch
// => fits without spill AND 4 waves/SIMD (round 5-10 lesson: occupancy steps on
// unified arch+acc total; 140 regs = 1 block/CU, spill = 176MB scratch traffic).
__global__ __launch_bounds__(512, 4)
void mlp_kernel(const float* __restrict__ x_world,
                const float* __restrict__ inv_poses,
                const float* __restrict__ b0, const float* __restrict__ b1,
                const float* __restrict__ b2, const float* __restrict__ w3,
                const float* __restrict__ b3, const f16* __restrict__ wf,
                float* __restrict__ out)
{
    __shared__ char lds[LDS_TOTAL];     // h[128][256] f16 | feat | predp

    f16*   feath = (f16*)(lds + LDS_FEAT);      // [128][40]
    float* predp = (float*)(lds + LDS_PREDP);   // [128][8]

    const int tid  = threadIdx.x;
    const int lane = tid & 63;
    const int wv   = tid >> 6;          // wave id 0..7 = channel group
    const int l15  = lane & 15;
    const int g    = lane >> 4;

    const int bid   = blockIdx.x;
    const int n_idx = bid >> 7;         // 128 blocks per pose
    const int bbase = (bid & 127) * TM;

    // ---- pose transform + positional encoding (4 threads per point) ----
    {
        const int p   = tid >> 2;       // 0..127
        const int sub = tid & 3;
        const int b   = bbase + p;
        const float xw0 = x_world[b*3+0], xw1 = x_world[b*3+1], xw2 = x_world[b*3+2];
        const float* P = inv_poses + n_idx * 16;
        float xl[3];
        #pragma unroll
        for (int x = 0; x < 3; ++x)
            xl[x] = P[x*4+3] + P[x*4+0]*xw0 + P[x*4+1]*xw1 + P[x*4+2]*xw2;

        auto put = [&](int c, float v) { feath[p*40 + c] = (f16)v; };
        if (sub == 0) {
            float* xla = out + OFF_XLA + ((size_t)n_idx * BPTS + b) * 3;
            #pragma unroll
            for (int x = 0; x < 3; ++x) { xla[x] = xl[x]; put(x, xl[x]); }
            put(39, 0.f);               // k-pad
        }
        #pragma unroll
        for (int t = 0; t < 3; ++t) {   // 12 sin/cos jobs, 3 per sub
            int j = sub * 3 + t;
            int o = j >> 1, fn = j & 1;
            float s = (float)(1 << o);
            #pragma unroll
            for (int x = 0; x < 3; ++x) {
                float a = xl[x] * s;
                put(3 + 6*o + 3*fn + x, fn ? cosf(a) : sinf(a));
            }
        }
    }
    __syncthreads();

    f32x4 acc[2][4];                    // [c2][q]: 32 channels x 64 points (one half)

    auto init_bias = [&](const float* bias) {
        #pragma unroll
        for (int c2 = 0; c2 < 2; ++c2) {
            f32x4 bv = *(const f32x4*)(bias + (wv + c2*8) * 16 + g * 4);
            #pragma unroll
            for (int q = 0; q < 4; ++q) acc[c2][q] = bv;
        }
    };
    auto packone = [&](f32x4 a) {
        return (f16x4){(f16)fmaxf(a[0],0.f), (f16)fmaxf(a[1],0.f),
                       (f16)fmaxf(a[2],0.f), (f16)fmaxf(a[3],0.f)};
    };
    // store 4 consecutive channels (ch = (wv+c2*8)*16 + g*4) for point row
    auto sthalf = [&](int half) {
        #pragma unroll
        for (int c2 = 0; c2 < 2; ++c2)
            #pragma unroll
            for (int q = 0; q < 4; ++q) {
                int cbyte = c2 * 256 + wv * 32 + g * 8;
                *(f16x4*)(lds + bswz((half*4 + q) * 16 + l15, cbyte))
                    = packone(acc[c2][q]);
            }
    };
    // one point-half accumulation pass over a 256-k hidden weight set
    auto accum_half = [&](int half, const f16* wfh, const f16* wfl) {
        #pragma unroll
        for (int kcg = 0; kcg < 8; ++kcg) {
            f16x8 bh[4];
            #pragma unroll
            for (int q = 0; q < 4; ++q)
                bh[q] = *(const f16x8*)(lds +
                          bswz((half*4 + q) * 16 + l15, kcg * 64 + g * 16));
            #pragma unroll
            for (int c2 = 0; c2 < 2; ++c2) {
                int off = (((wv + c2*8) * 8 + kcg) * 64 + lane) * 8;
                f16x8 wh = *(const f16x8*)(wfh + off);
                f16x8 wl = *(const f16x8*)(wfl + off);
                #pragma unroll
                for (int q = 0; q < 4; ++q) {
                    acc[c2][q] = MFMA16(wh, bh[q], acc[c2][q]);
                    acc[c2][q] = MFMA16(wl, bh[q], acc[c2][q]);
                }
            }
        }
    };

    // ---- layer 0: feat -> h0, per point-half (h buffer virgin: no pre-barrier) ----
    {
        const f16x8 z = {};
        #pragma unroll
        for (int half = 0; half < 2; ++half) {
            init_bias(b0);
            #pragma unroll
            for (int kc = 0; kc < 2; ++kc) {
                f16x8 ah[4];
                #pragma unroll
                for (int q = 0; q < 4; ++q) {
                    int p = (half*4 + q) * 16 + l15;
                    if (kc == 0)      ah[q] = *(const f16x8*)&feath[p*40 + g*8];
                    else if (g == 0)  ah[q] = *(const f16x8*)&feath[p*40 + 32];
                    else              ah[q] = z;
                }
                #pragma unroll
                for (int c2 = 0; c2 < 2; ++c2) {
                    int off = (((wv + c2*8) * 2 + kc) * 64 + lane) * 8;
                    f16x8 wh = *(const f16x8*)(wf + WS_W0H + off);
                    f16x8 wl = *(const f16x8*)(wf + WS_W0L + off);
                    #pragma unroll
                    for (int q = 0; q < 4; ++q) {
                        acc[c2][q] = MFMA16(wh, ah[q], acc[c2][q]);
                        acc[c2][q] = MFMA16(wl, ah[q], acc[c2][q]);
                    }
                }
            }
            sthalf(half);
        }
    }
    __syncthreads();                    // h0 complete & visible

    // ---- layer 1: h0 -> h1, point-half in-place overwrite ----
    init_bias(b1);
    accum_half(0, wf + WS_W1H, wf + WS_W1L);
    __syncthreads();                    // all waves done reading rows 0..63 (h0)
    sthalf(0);                          // rows 0..63 become h1
    init_bias(b1);
    accum_half(1, wf + WS_W1H, wf + WS_W1L);   // rows 64..127 still h0
    __syncthreads();                    // all waves done reading rows 64..127
    sthalf(1);
    __syncthreads();                    // h1 complete & visible

    // ---- layer 2 + layer 3 fused: pred from registers, no stores ----
    {
        float pp[8] = {};
        #pragma unroll
        for (int half = 0; half < 2; ++half) {
            init_bias(b2);
            accum_half(half, wf + WS_W2H, wf + WS_W2L);
            #pragma unroll
            for (int c2 = 0; c2 < 2; ++c2) {
                f32x4 wvv = *(const f32x4*)(w3 + (wv + c2*8) * 16 + g * 4);
                #pragma unroll
                for (int q = 0; q < 4; ++q)
                    #pragma unroll
                    for (int r = 0; r < 4; ++r)
                        pp[half*4+q] = fmaf(fmaxf(acc[c2][q][r], 0.f), wvv[r],
                                            pp[half*4+q]);
            }
        }
        #pragma unroll
        for (int pt = 0; pt < 8; ++pt) {
            pp[pt] += __shfl_xor(pp[pt], 16);    // reduce over g (channel groups)
            pp[pt] += __shfl_xor(pp[pt], 32);
        }
        if (g == 0) {
            #pragma unroll
            for (int pt = 0; pt < 8; ++pt)
                predp[(pt * 16 + l15) * 8 + wv] = pp[pt];
        }
    }
    __syncthreads();
    if (tid < TM) {
        float s = b3[0];
        #pragma unroll
        for (int j = 0; j < 8; ++j) s += predp[tid * 8 + j];
        out[OFF_PRED + (size_t)(bbase + tid) * NPOSE + n_idx] = s;
    }
}

// per-point output writer (shared by select & fixup)
__device__ __forceinline__ void write_point(int b, int idx,
                                            const float* __restrict__ x_world,
                                            const float* __restrict__ inv_poses,
                                            const float* __restrict__ vector,
                                            float* __restrict__ out)
{
    float* me = out + OFF_MINENC + (size_t)b * NPOSE;
    #pragma unroll
    for (int n = 0; n < NPOSE; ++n) me[n] = (n == idx) ? 1.f : 0.f;

    const float* P = inv_poses + idx * 16;
    float* pq = out + OFF_POSEQ + (size_t)b * 16;
    #pragma unroll
    for (int m = 0; m < 16; ++m) pq[m] = P[m];

    const float xw0 = x_world[b*3+0], xw1 = x_world[b*3+1], xw2 = x_world[b*3+2];
    float* xl = out + OFF_XLOCAL + (size_t)b * 3;
    #pragma unroll
    for (int x = 0; x < 3; ++x)
        xl[x] = P[x*4+3] + P[x*4+0]*xw0 + P[x*4+1]*xw1 + P[x*4+2]*xw2;

    out[OFF_CLASS + b] = (float)idx;

    const float* vq = vector + idx * KV;
    float* ov = out + OFF_VECQ + (size_t)b * KV;
    #pragma unroll
    for (int m = 0; m < KV; ++m) ov[m] = vq[m];
}

__global__ __launch_bounds__(256)
void select_kernel(const float* __restrict__ x_world,
                   const float* __restrict__ inv_poses,
                   const float* __restrict__ vector,
                   float* __restrict__ out,
                   int* __restrict__ cnt, int2* __restrict__ pairs,
                   float* __restrict__ exact)
{
    const int b = blockIdx.x * 256 + threadIdx.x;
    if (b >= BPTS) return;

    const float* pr = out + OFF_PRED + (size_t)b * NPOSE;
    float best = pr[0], best2 = 3.4e38f;
    int idx = 0;
    #pragma unroll
    for (int n = 1; n < NPOSE; ++n) {
        float v = pr[n];
        if (v < best) { best2 = best; best = v; idx = n; }
        else if (v < best2) { best2 = v; }
    }

    if (best2 - best >= TAU) {
        write_point(b, idx, x_world, inv_poses, vector, out);
    } else {
        #pragma unroll
        for (int n = 0; n < NPOSE; ++n) {
            float v = pr[n];
            if (v < best + TAU) {
                exact[b * NPOSE + n] = v;
                int slot = atomicAdd(cnt, 1);
                if (slot < PAIR_CAP) pairs[slot] = make_int2(b, n);
            }
        }
    }
}

// fp32 exact MLP for flagged pairs: 32 pairs/chunk, 512 threads, 2-row tiles
template<int KDIM, int RS>
__device__ __forceinline__ void gemm32r2(const float* __restrict__ W,
                                         const float* __restrict__ B,
                                         const float (*in)[RS],
                                         float acc[2][8], int tc, int tr)
{
    {
        float4 bA = *(const float4*)(B + tc*4);
        float4 bB = *(const float4*)(B + 128 + tc*4);
        #pragma unroll
        for (int i = 0; i < 2; ++i) {
            acc[i][0]=bA.x; acc[i][1]=bA.y; acc[i][2]=bA.z; acc[i][3]=bA.w;
            acc[i][4]=bB.x; acc[i][5]=bB.y; acc[i][6]=bB.z; acc[i][7]=bB.w;
        }
    }
    constexpr int K4 = KDIM & ~3;
    #pragma unroll 2
    for (int k = 0; k < K4; k += 4) {
        float4 a4[2];
        #pragma unroll
        for (int i = 0; i < 2; ++i) a4[i] = *(const float4*)&in[tr*2+i][k];
        #pragma unroll
        for (int kk = 0; kk < 4; ++kk) {
            float4 wA = *(const float4*)(W + (size_t)(k+kk)*HD + tc*4);
            float4 wB = *(const float4*)(W + (size_t)(k+kk)*HD + 128 + tc*4);
            #pragma unroll
            for (int i = 0; i < 2; ++i) {
                const float a = (kk==0) ? a4[i].x : (kk==1) ? a4[i].y
                              : (kk==2) ? a4[i].z : a4[i].w;
                acc[i][0] = fmaf(a, wA.x, acc[i][0]);
                acc[i][1] = fmaf(a, wA.y, acc[i][1]);
                acc[i][2] = fmaf(a, wA.z, acc[i][2]);
                acc[i][3] = fmaf(a, wA.w, acc[i][3]);
                acc[i][4] = fmaf(a, wB.x, acc[i][4]);
                acc[i][5] = fmaf(a, wB.y, acc[i][5]);
                acc[i][6] = fmaf(a, wB.z, acc[i][6]);
                acc[i][7] = fmaf(a, wB.w, acc[i][7]);
            }
        }
    }
    if constexpr (K4 < KDIM) {
        #pragma unroll
        for (int k = K4; k < KDIM; ++k) {
            float4 wA = *(const float4*)(W + (size_t)k*HD + tc*4);
            float4 wB = *(const float4*)(W + (size_t)k*HD + 128 + tc*4);
            #pragma unroll
            for (int i = 0; i < 2; ++i) {
                const float a = in[tr*2+i][k];
                acc[i][0] = fmaf(a, wA.x, acc[i][0]);
                acc[i][1] = fmaf(a, wA.y, acc[i][1]);
                acc[i][2] = fmaf(a, wA.z, acc[i][2]);
                acc[i][3] = fmaf(a, wA.w, acc[i][3]);
                acc[i][4] = fmaf(a, wB.x, acc[i][4]);
                acc[i][5] = fmaf(a, wB.y, acc[i][5]);
                acc[i][6] = fmaf(a, wB.z, acc[i][6]);
                acc[i][7] = fmaf(a, wB.w, acc[i][7]);
            }
        }
    }
}

__global__ __launch_bounds__(512, 2)
void recompute_kernel(const float* __restrict__ x_world,
                      const float* __restrict__ inv_poses,
                      const float* __restrict__ w0, const float* __restrict__ b0,
                      const float* __restrict__ w1, const float* __restrict__ b1,
                      const float* __restrict__ w2, const float* __restrict__ b2,
                      const float* __restrict__ w3, const float* __restrict__ b3,
                      const int* __restrict__ cnt, const int2* __restrict__ pairs,
                      float* __restrict__ exact)
{
    __shared__ float feat[32][44];
    __shared__ float h[32][256];
    __shared__ int2  pl[32];

    const int tid = threadIdx.x;
    const int total = min(*cnt, PAIR_CAP);
    const int tc = tid & 31, tr = tid >> 5;     // 16 row-groups x 2 rows

    for (int base = blockIdx.x * 32; base < total; base += gridDim.x * 32) {
        const int nrows = min(32, total - base);
        if (tid < 32) pl[tid] = (tid < nrows) ? pairs[base + tid] : make_int2(0, 0);
        __syncthreads();
        // embed: 16 threads per row
        {
            const int r = tid >> 4, sub = tid & 15;
            const int2 pp = pl[r];
            const int b = pp.x;
            const float xw0 = x_world[b*3+0], xw1 = x_world[b*3+1], xw2 = x_world[b*3+2];
            const float* P = inv_poses + pp.y * 16;
            float xl[3];
            #pragma unroll
            for (int x = 0; x < 3; ++x)
                xl[x] = P[x*4+3] + P[x*4+0]*xw0 + P[x*4+1]*xw1 + P[x*4+2]*xw2;
            if (sub == 12) {
                #pragma unroll
                for (int x = 0; x < 3; ++x) feat[r][x] = xl[x];
            }
            if (sub < 12) {
                int o = sub >> 1, fn = sub & 1;
                float s = (float)(1 << o);
                #pragma unroll
                for (int x = 0; x < 3; ++x) {
                    float a = xl[x] * s;
                    feat[r][3 + 6*o + 3*fn + x] = fn ? cosf(a) : sinf(a);
                }
            }
        }
        __syncthreads();

        float acc[2][8];
        gemm32r2<39, 44>(w0, b0, feat, acc, tc, tr);
        #pragma unroll
        for (int i = 0; i < 2; ++i)
            #pragma unroll
            for (int j = 0; j < 8; ++j) {
                int col = (j < 4) ? tc*4 + j : 128 + tc*4 + (j-4);
                h[tr*2+i][col] = fmaxf(acc[i][j], 0.f);
            }
        __syncthreads();
        gemm32r2<HD, HD>(w1, b1, h, acc, tc, tr);
        __syncthreads();
        #pragma unroll
        for (int i = 0; i < 2; ++i)
            #pragma unroll
            for (int j = 0; j < 8; ++j) {
                int col = (j < 4) ? tc*4 + j : 128 + tc*4 + (j-4);
                h[tr*2+i][col] = fmaxf(acc[i][j], 0.f);
            }
        __syncthreads();
        gemm32r2<HD, HD>(w2, b2, h, acc, tc, tr);
        __syncthreads();
        #pragma unroll
        for (int i = 0; i < 2; ++i)
            #pragma unroll
            for (int j = 0; j < 8; ++j) {
                int col = (j < 4) ? tc*4 + j : 128 + tc*4 + (j-4);
                h[tr*2+i][col] = fmaxf(acc[i][j], 0.f);
            }
        __syncthreads();
        if (tid < nrows) {
            float s = b3[0];
            for (int c = 0; c < HD; ++c) s = fmaf(h[tid][c], w3[c], s);
            exact[pl[tid].x * NPOSE + pl[tid].y] = s;
        }
        __syncthreads();
    }
}

__global__ __launch_bounds__(256)
void fixup_kernel(const float* __restrict__ x_world,
                  const float* __restrict__ inv_poses,
                  const float* __restrict__ vector,
                  float* __restrict__ out,
                  const float* __restrict__ exact)
{
    const int b = blockIdx.x * 256 + threadIdx.x;
    if (b >= BPTS) return;

    const float* pr = out + OFF_PRED + (size_t)b * NPOSE;
    float best = pr[0], best2 = 3.4e38f;
    #pragma unroll
    for (int n = 1; n < NPOSE; ++n) {
        float v = pr[n];
        if (v < best) { best2 = best; best = v; }
        else if (v < best2) { best2 = v; }
    }
    if (best2 - best >= TAU) return;

    float ebest = 3.4e38f;
    int idx = 0;
    #pragma unroll
    for (int n = 0; n < NPOSE; ++n) {
        if (pr[n] < best + TAU) {
            float v = exact[b * NPOSE + n];
            if (v < ebest) { ebest = v; idx = n; }
        }
    }
    write_point(b, idx, x_world, inv_poses, vector, out);
}

extern "C" void kernel_launch(void* const* d_in, const int* in_sizes, int n_in,
                              void* d_out, int out_size, void* d_ws, size_t ws_size,
                              hipStream_t stream)
{
    const float* x_world   = (const float*)d_in[0];
    const float* inv_poses = (const float*)d_in[1];
    const float* vector    = (const float*)d_in[2];
    const float* w0 = (const float*)d_in[3];
    const float* b0 = (const float*)d_in[4];
    const float* w1 = (const float*)d_in[5];
    const float* b1 = (const float*)d_in[6];
    const float* w2 = (const float*)d_in[7];
    const float* b2 = (const float*)d_in[8];
    const float* w3 = (const float*)d_in[9];
    const float* b3 = (const float*)d_in[10];
    float* out = (float*)d_out;

    char*  ws    = (char*)d_ws;
    f16*   wf    = (f16*)ws;
    int*   cnt   = (int*)(ws + CNT_B);
    int2*  pairs = (int2*)(ws + PAIRS_B);
    float* exact = (float*)(ws + EXACT_B);

    prep_all<<<dim3(576), dim3(256), 0, stream>>>(w0, w1, w2, wf, cnt);

    mlp_kernel<<<dim3(NPOSE * BPTS / TM), dim3(512), 0, stream>>>(
        x_world, inv_poses, b0, b1, b2, w3, b3, wf, out);
    select_kernel<<<dim3(BPTS / 256), dim3(256), 0, stream>>>(
        x_world, inv_poses, vector, out, cnt, pairs, exact);
    recompute_kernel<<<dim3(512), dim3(512), 0, stream>>>(
        x_world, inv_poses, w0, b0, w1, b1, w2, b2, w3, b3, cnt, pairs, exact);
    fixup_kernel<<<dim3(BPTS / 256), dim3(256), 0, stream>>>(
        x_world, inv_poses, vector, out, exact);
}

// Round 12
// 389.834 us; speedup vs baseline: 1.3621x; 1.3621x over previous
//
#include <hip/hip_runtime.h>
#include <cmath>

namespace {
constexpr int BPTS  = 16384;
constexpr int NPOSE = 32;
constexpr int KV    = 8;
constexpr int HD    = 256;
constexpr int TM    = 128;      // points per block (mlp)
constexpr float TAU = 0.015f;   // argmin ambiguity threshold (~3x max 2-term err)

constexpr size_t OFF_XLOCAL = 0;
constexpr size_t OFF_XLA    = (size_t)BPTS * 3;
constexpr size_t OFF_MINENC = OFF_XLA + (size_t)NPOSE * BPTS * 3;
constexpr size_t OFF_POSEQ  = OFF_MINENC + (size_t)BPTS * NPOSE;
constexpr size_t OFF_CLASS  = OFF_POSEQ + (size_t)BPTS * 16;
constexpr size_t OFF_PRED   = OFF_CLASS + (size_t)BPTS;
constexpr size_t OFF_VECQ   = OFF_PRED + (size_t)BPTS * NPOSE;

// workspace: f16 weight fragments (hi/lo), then reverify structures
constexpr size_t WS_W0H = 0;         // f16 element offsets
constexpr size_t WS_W0L = 16384;
constexpr size_t WS_W1H = 32768;
constexpr size_t WS_W1L = 98304;
constexpr size_t WS_W2H = 163840;
constexpr size_t WS_W2L = 229376;
constexpr size_t WB_END   = 589824;              // bytes
constexpr size_t CNT_B    = WB_END;
constexpr size_t PAIRS_B  = WB_END + 1024;
constexpr int    PAIR_CAP = 65536;
constexpr size_t EXACT_B  = PAIRS_B + (size_t)PAIR_CAP * 8;

// LDS layout (mlp): h buffer 64KB | feat 10KB | predp 4KB = 78KB -> 2 blocks/CU
constexpr int LDS_FEAT  = 65536;
constexpr int LDS_PREDP = 65536 + 10240;
constexpr int LDS_TOTAL = 65536 + 10240 + 4096;
}

typedef _Float16 f16;
typedef __attribute__((ext_vector_type(4))) _Float16 f16x4;
typedef __attribute__((ext_vector_type(8))) _Float16 f16x8;
typedef __attribute__((ext_vector_type(4))) float    f32x4;

#define MFMA16(a, b, c) __builtin_amdgcn_mfma_f32_16x16x32_f16((a), (b), (c), 0, 0, 0)

// ---- merged weight prep (+ cnt zero): split fp32 W[k][ch] into hi/lo f16 frags.
// idx = ((cht*KC + kc)*64 + lane)*8 + e -> W[k=kc*32+(lane>>4)*8+e][ch=cht*16+(lane&15)]
__global__ __launch_bounds__(256)
void prep_all(const float* __restrict__ w0, const float* __restrict__ w1,
              const float* __restrict__ w2, f16* __restrict__ wf, int* __restrict__ cnt)
{
    const int bid = blockIdx.x, tid = threadIdx.x;
    if (bid == 0 && tid == 0) *cnt = 0;
    if (bid < 64) {                       // w0: KC=2, 16384 frags
        int i = bid * 256 + tid;
        int e  = i & 7;
        int l  = (i >> 3) & 63;
        int kc = (i >> 9) & 1;
        int nt = i >> 10;
        int k   = kc * 32 + ((l >> 4) << 3) + e;
        int col = nt * 16 + (l & 15);
        float v = (k < 39) ? w0[k * HD + col] : 0.f;
        f16 hi = (f16)v;
        wf[WS_W0H + i] = hi;
        wf[WS_W0L + i] = (f16)(v - (float)hi);
    } else {                              // w1/w2: KC=8, 65536 frags each
        const bool is1 = bid < 320;
        const float* w = is1 ? w1 : w2;
        int i = (bid - (is1 ? 64 : 320)) * 256 + tid;
        int e  = i & 7;
        int l  = (i >> 3) & 63;
        int kc = (i >> 9) & 7;
        int nt = i >> 12;
        int k   = kc * 32 + ((l >> 4) << 3) + e;
        int col = nt * 16 + (l & 15);
        float v = w[k * HD + col];
        f16 hi = (f16)v;
        wf[(is1 ? WS_W1H : WS_W2H) + i] = hi;
        wf[(is1 ? WS_W1L : WS_W2L) + i] = (f16)(v - (float)hi);
    }
}

// swizzled byte address in the 512B full-width row: p 0..127, cbyte 0..511
__device__ __forceinline__ int bswz(int p, int cbyte) {
    return p * 512 + (cbyte ^ ((p & 15) << 4));
}

// TM=128 full-pass: weights loaded ONCE per block (2.4GB L2 total, half of TM=64).
// (512,4) = 128-reg total budget: acc 64 AGPR + ~55 arch. The r9 spill came from
// full unroll hoisting loads; #pragma unroll 1 on kcg caps live arch regs.
__global__ __launch_bounds__(512, 4)
void mlp_kernel(const float* __restrict__ x_world,
                const float* __restrict__ inv_poses,
                const float* __restrict__ b0, const float* __restrict__ b1,
                const float* __restrict__ b2, const float* __restrict__ w3,
                const float* __restrict__ b3, const f16* __restrict__ wf,
                float* __restrict__ out)
{
    __shared__ char lds[LDS_TOTAL];     // h[128][256] f16 | feat | predp

    f16*   feath = (f16*)(lds + LDS_FEAT);      // [128][40]
    float* predp = (float*)(lds + LDS_PREDP);   // [128][8]

    const int tid  = threadIdx.x;
    const int lane = tid & 63;
    const int wv   = tid >> 6;          // wave id 0..7 = channel group
    const int l15  = lane & 15;
    const int g    = lane >> 4;

    const int bid   = blockIdx.x;
    const int n_idx = bid >> 7;         // 128 blocks per pose
    const int bbase = (bid & 127) * TM;

    // wave wv owns channels cht=wv (cols 0..127 half) and wv+8 (cols 128..255 half)
    // for ALL 128 points: each weight fragment read exactly once per block.

    // ---- pose transform + positional encoding (4 threads per point) ----
    {
        const int p   = tid >> 2;       // 0..127
        const int sub = tid & 3;
        const int b   = bbase + p;
        const float xw0 = x_world[b*3+0], xw1 = x_world[b*3+1], xw2 = x_world[b*3+2];
        const float* P = inv_poses + n_idx * 16;
        float xl[3];
        #pragma unroll
        for (int x = 0; x < 3; ++x)
            xl[x] = P[x*4+3] + P[x*4+0]*xw0 + P[x*4+1]*xw1 + P[x*4+2]*xw2;

        auto put = [&](int c, float v) { feath[p*40 + c] = (f16)v; };
        if (sub == 0) {
            float* xla = out + OFF_XLA + ((size_t)n_idx * BPTS + b) * 3;
            #pragma unroll
            for (int x = 0; x < 3; ++x) { xla[x] = xl[x]; put(x, xl[x]); }
            put(39, 0.f);               // k-pad
        }
        #pragma unroll
        for (int t = 0; t < 3; ++t) {   // 12 sin/cos jobs, 3 per sub
            int j = sub * 3 + t;
            int o = j >> 1, fn = j & 1;
            float s = (float)(1 << o);
            #pragma unroll
            for (int x = 0; x < 3; ++x) {
                float a = xl[x] * s;
                put(3 + 6*o + 3*fn + x, fn ? cosf(a) : sinf(a));
            }
        }
    }
    __syncthreads();

    f32x4 acc[2][8];                    // [c2][pt]: 32 ch x 128 pts (64 AGPR)

    auto init_bias = [&](const float* bias) {
        #pragma unroll
        for (int c2 = 0; c2 < 2; ++c2) {
            f32x4 bv = *(const f32x4*)(bias + (wv + c2*8) * 16 + g * 4);
            #pragma unroll
            for (int pt = 0; pt < 8; ++pt) acc[c2][pt] = bv;
        }
    };
    auto packone = [&](f32x4 a) {
        return (f16x4){(f16)fmaxf(a[0],0.f), (f16)fmaxf(a[1],0.f),
                       (f16)fmaxf(a[2],0.f), (f16)fmaxf(a[3],0.f)};
    };
    auto st_all = [&]() {               // relu+pack all 16 (c2,pt) frags -> h
        #pragma unroll
        for (int c2 = 0; c2 < 2; ++c2)
            #pragma unroll
            for (int pt = 0; pt < 8; ++pt) {
                int cbyte = c2 * 256 + wv * 32 + g * 8;
                *(f16x4*)(lds + bswz(pt * 16 + l15, cbyte)) = packone(acc[c2][pt]);
            }
    };
    // hidden-layer accumulate: weights once per kcg (outer), both point halves inner
    auto hidden_accum = [&](const f16* wfh, const f16* wfl) {
        const f16* wph0 = wfh + ((size_t)(wv    ) * 4096 + lane * 8);
        const f16* wpl0 = wfl + ((size_t)(wv    ) * 4096 + lane * 8);
        const f16* wph1 = wfh + ((size_t)(wv + 8) * 4096 + lane * 8);
        const f16* wpl1 = wfl + ((size_t)(wv + 8) * 4096 + lane * 8);
        #pragma unroll 1
        for (int kcg = 0; kcg < 8; ++kcg) {
            f16x8 wh0 = *(const f16x8*)(wph0 + kcg * 512);
            f16x8 wl0 = *(const f16x8*)(wpl0 + kcg * 512);
            f16x8 wh1 = *(const f16x8*)(wph1 + kcg * 512);
            f16x8 wl1 = *(const f16x8*)(wpl1 + kcg * 512);
            #pragma unroll
            for (int half = 0; half < 2; ++half) {
                f16x8 bh[4];
                #pragma unroll
                for (int q = 0; q < 4; ++q)
                    bh[q] = *(const f16x8*)(lds +
                              bswz((half*4 + q) * 16 + l15, kcg * 64 + g * 16));
                #pragma unroll
                for (int q = 0; q < 4; ++q) {
                    acc[0][half*4+q] = MFMA16(wh0, bh[q], acc[0][half*4+q]);
                    acc[0][half*4+q] = MFMA16(wl0, bh[q], acc[0][half*4+q]);
                    acc[1][half*4+q] = MFMA16(wh1, bh[q], acc[1][half*4+q]);
                    acc[1][half*4+q] = MFMA16(wl1, bh[q], acc[1][half*4+q]);
                }
            }
        }
    };

    // ---- layer 0: feat(39, padded 64) -> acc ----
    init_bias(b0);
    {
        const f16x8 z = {};
        #pragma unroll
        for (int kc = 0; kc < 2; ++kc) {
            f16x8 wh0 = *(const f16x8*)(wf + WS_W0H + ((wv*2      + kc) * 64 + lane) * 8);
            f16x8 wl0 = *(const f16x8*)(wf + WS_W0L + ((wv*2      + kc) * 64 + lane) * 8);
            f16x8 wh1 = *(const f16x8*)(wf + WS_W0H + (((wv+8)*2  + kc) * 64 + lane) * 8);
            f16x8 wl1 = *(const f16x8*)(wf + WS_W0L + (((wv+8)*2  + kc) * 64 + lane) * 8);
            #pragma unroll
            for (int half = 0; half < 2; ++half) {
                f16x8 ah[4];
                #pragma unroll
                for (int q = 0; q < 4; ++q) {
                    int p = (half*4 + q) * 16 + l15;
                    if (kc == 0)      ah[q] = *(const f16x8*)&feath[p*40 + g*8];
                    else if (g == 0)  ah[q] = *(const f16x8*)&feath[p*40 + 32];
                    else              ah[q] = z;
                }
                #pragma unroll
                for (int q = 0; q < 4; ++q) {
                    acc[0][half*4+q] = MFMA16(wh0, ah[q], acc[0][half*4+q]);
                    acc[0][half*4+q] = MFMA16(wl0, ah[q], acc[0][half*4+q]);
                    acc[1][half*4+q] = MFMA16(wh1, ah[q], acc[1][half*4+q]);
                    acc[1][half*4+q] = MFMA16(wl1, ah[q], acc[1][half*4+q]);
                }
            }
        }
    }
    st_all();                           // h region disjoint from feath: no pre-barrier
    __syncthreads();                    // h0 complete & visible

    // ---- layer 1 ----
    init_bias(b1);
    hidden_accum(wf + WS_W1H, wf + WS_W1L);
    __syncthreads();                    // all waves done reading h0
    st_all();
    __syncthreads();                    // h1 complete & visible

    // ---- layer 2 + layer 3 fused: pred from registers, no stores ----
    init_bias(b2);
    hidden_accum(wf + WS_W2H, wf + WS_W2L);
    {
        float pp[8] = {};
        #pragma unroll
        for (int c2 = 0; c2 < 2; ++c2) {
            f32x4 wvv = *(const f32x4*)(w3 + (wv + c2*8) * 16 + g * 4);
            #pragma unroll
            for (int pt = 0; pt < 8; ++pt)
                #pragma unroll
                for (int r = 0; r < 4; ++r)
                    pp[pt] = fmaf(fmaxf(acc[c2][pt][r], 0.f), wvv[r], pp[pt]);
        }
        #pragma unroll
        for (int pt = 0; pt < 8; ++pt) {
            pp[pt] += __shfl_xor(pp[pt], 16);    // reduce over g (channel groups)
            pp[pt] += __shfl_xor(pp[pt], 32);
        }
        if (g == 0) {
            #pragma unroll
            for (int pt = 0; pt < 8; ++pt)
                predp[(pt * 16 + l15) * 8 + wv] = pp[pt];
        }
    }
    __syncthreads();
    if (tid < TM) {
        float s = b3[0];
        #pragma unroll
        for (int j = 0; j < 8; ++j) s += predp[tid * 8 + j];
        out[OFF_PRED + (size_t)(bbase + tid) * NPOSE + n_idx] = s;
    }
}

// per-point output writer (shared by select & fixup)
__device__ __forceinline__ void write_point(int b, int idx,
                                            const float* __restrict__ x_world,
                                            const float* __restrict__ inv_poses,
                                            const float* __restrict__ vector,
                                            float* __restrict__ out)
{
    float* me = out + OFF_MINENC + (size_t)b * NPOSE;
    #pragma unroll
    for (int n = 0; n < NPOSE; ++n) me[n] = (n == idx) ? 1.f : 0.f;

    const float* P = inv_poses + idx * 16;
    float* pq = out + OFF_POSEQ + (size_t)b * 16;
    #pragma unroll
    for (int m = 0; m < 16; ++m) pq[m] = P[m];

    const float xw0 = x_world[b*3+0], xw1 = x_world[b*3+1], xw2 = x_world[b*3+2];
    float* xl = out + OFF_XLOCAL + (size_t)b * 3;
    #pragma unroll
    for (int x = 0; x < 3; ++x)
        xl[x] = P[x*4+3] + P[x*4+0]*xw0 + P[x*4+1]*xw1 + P[x*4+2]*xw2;

    out[OFF_CLASS + b] = (float)idx;

    const float* vq = vector + idx * KV;
    float* ov = out + OFF_VECQ + (size_t)b * KV;
    #pragma unroll
    for (int m = 0; m < KV; ++m) ov[m] = vq[m];
}

__global__ __launch_bounds__(256)
void select_kernel(const float* __restrict__ x_world,
                   const float* __restrict__ inv_poses,
                   const float* __restrict__ vector,
                   float* __restrict__ out,
                   int* __restrict__ cnt, int2* __restrict__ pairs,
                   float* __restrict__ exact)
{
    const int b = blockIdx.x * 256 + threadIdx.x;
    if (b >= BPTS) return;

    const float* pr = out + OFF_PRED + (size_t)b * NPOSE;
    float best = pr[0], best2 = 3.4e38f;
    int idx = 0;
    #pragma unroll
    for (int n = 1; n < NPOSE; ++n) {
        float v = pr[n];
        if (v < best) { best2 = best; best = v; idx = n; }
        else if (v < best2) { best2 = v; }
    }

    if (best2 - best >= TAU) {
        write_point(b, idx, x_world, inv_poses, vector, out);
    } else {
        #pragma unroll
        for (int n = 0; n < NPOSE; ++n) {
            float v = pr[n];
            if (v < best + TAU) {
                exact[b * NPOSE + n] = v;
                int slot = atomicAdd(cnt, 1);
                if (slot < PAIR_CAP) pairs[slot] = make_int2(b, n);
            }
        }
    }
}

// fp32 exact MLP for flagged pairs: 32 pairs/chunk, 512 threads, 2-row tiles
template<int KDIM, int RS>
__device__ __forceinline__ void gemm32r2(const float* __restrict__ W,
                                         const float* __restrict__ B,
                                         const float (*in)[RS],
                                         float acc[2][8], int tc, int tr)
{
    {
        float4 bA = *(const float4*)(B + tc*4);
        float4 bB = *(const float4*)(B + 128 + tc*4);
        #pragma unroll
        for (int i = 0; i < 2; ++i) {
            acc[i][0]=bA.x; acc[i][1]=bA.y; acc[i][2]=bA.z; acc[i][3]=bA.w;
            acc[i][4]=bB.x; acc[i][5]=bB.y; acc[i][6]=bB.z; acc[i][7]=bB.w;
        }
    }
    constexpr int K4 = KDIM & ~3;
    #pragma unroll 2
    for (int k = 0; k < K4; k += 4) {
        float4 a4[2];
        #pragma unroll
        for (int i = 0; i < 2; ++i) a4[i] = *(const float4*)&in[tr*2+i][k];
        #pragma unroll
        for (int kk = 0; kk < 4; ++kk) {
            float4 wA = *(const float4*)(W + (size_t)(k+kk)*HD + tc*4);
            float4 wB = *(const float4*)(W + (size_t)(k+kk)*HD + 128 + tc*4);
            #pragma unroll
            for (int i = 0; i < 2; ++i) {
                const float a = (kk==0) ? a4[i].x : (kk==1) ? a4[i].y
                              : (kk==2) ? a4[i].z : a4[i].w;
                acc[i][0] = fmaf(a, wA.x, acc[i][0]);
                acc[i][1] = fmaf(a, wA.y, acc[i][1]);
                acc[i][2] = fmaf(a, wA.z, acc[i][2]);
                acc[i][3] = fmaf(a, wA.w, acc[i][3]);
                acc[i][4] = fmaf(a, wB.x, acc[i][4]);
                acc[i][5] = fmaf(a, wB.y, acc[i][5]);
                acc[i][6] = fmaf(a, wB.z, acc[i][6]);
                acc[i][7] = fmaf(a, wB.w, acc[i][7]);
            }
        }
    }
    if constexpr (K4 < KDIM) {
        #pragma unroll
        for (int k = K4; k < KDIM; ++k) {
            float4 wA = *(const float4*)(W + (size_t)k*HD + tc*4);
            float4 wB = *(const float4*)(W + (size_t)k*HD + 128 + tc*4);
            #pragma unroll
            for (int i = 0; i < 2; ++i) {
                const float a = in[tr*2+i][k];
                acc[i][0] = fmaf(a, wA.x, acc[i][0]);
                acc[i][1] = fmaf(a, wA.y, acc[i][1]);
                acc[i][2] = fmaf(a, wA.z, acc[i][2]);
                acc[i][3] = fmaf(a, wA.w, acc[i][3]);
                acc[i][4] = fmaf(a, wB.x, acc[i][4]);
                acc[i][5] = fmaf(a, wB.y, acc[i][5]);
                acc[i][6] = fmaf(a, wB.z, acc[i][6]);
                acc[i][7] = fmaf(a, wB.w, acc[i][7]);
            }
        }
    }
}

__global__ __launch_bounds__(512, 2)
void recompute_kernel(const float* __restrict__ x_world,
                      const float* __restrict__ inv_poses,
                      const float* __restrict__ w0, const float* __restrict__ b0,
                      const float* __restrict__ w1, const float* __restrict__ b1,
                      const float* __restrict__ w2, const float* __restrict__ b2,
                      const float* __restrict__ w3, const float* __restrict__ b3,
                      const int* __restrict__ cnt, const int2* __restrict__ pairs,
                      float* __restrict__ exact)
{
    __shared__ float feat[32][44];
    __shared__ float h[32][256];
    __shared__ int2  pl[32];

    const int tid = threadIdx.x;
    const int total = min(*cnt, PAIR_CAP);
    const int tc = tid & 31, tr = tid >> 5;     // 16 row-groups x 2 rows

    for (int base = blockIdx.x * 32; base < total; base += gridDim.x * 32) {
        const int nrows = min(32, total - base);
        if (tid < 32) pl[tid] = (tid < nrows) ? pairs[base + tid] : make_int2(0, 0);
        __syncthreads();
        // embed: 16 threads per row
        {
            const int r = tid >> 4, sub = tid & 15;
            const int2 pp = pl[r];
            const int b = pp.x;
            const float xw0 = x_world[b*3+0], xw1 = x_world[b*3+1], xw2 = x_world[b*3+2];
            const float* P = inv_poses + pp.y * 16;
            float xl[3];
            #pragma unroll
            for (int x = 0; x < 3; ++x)
                xl[x] = P[x*4+3] + P[x*4+0]*xw0 + P[x*4+1]*xw1 + P[x*4+2]*xw2;
            if (sub == 12) {
                #pragma unroll
                for (int x = 0; x < 3; ++x) feat[r][x] = xl[x];
            }
            if (sub < 12) {
                int o = sub >> 1, fn = sub & 1;
                float s = (float)(1 << o);
                #pragma unroll
                for (int x = 0; x < 3; ++x) {
                    float a = xl[x] * s;
                    feat[r][3 + 6*o + 3*fn + x] = fn ? cosf(a) : sinf(a);
                }
            }
        }
        __syncthreads();

        float acc[2][8];
        gemm32r2<39, 44>(w0, b0, feat, acc, tc, tr);
        #pragma unroll
        for (int i = 0; i < 2; ++i)
            #pragma unroll
            for (int j = 0; j < 8; ++j) {
                int col = (j < 4) ? tc*4 + j : 128 + tc*4 + (j-4);
                h[tr*2+i][col] = fmaxf(acc[i][j], 0.f);
            }
        __syncthreads();
        gemm32r2<HD, HD>(w1, b1, h, acc, tc, tr);
        __syncthreads();
        #pragma unroll
        for (int i = 0; i < 2; ++i)
            #pragma unroll
            for (int j = 0; j < 8; ++j) {
                int col = (j < 4) ? tc*4 + j : 128 + tc*4 + (j-4);
                h[tr*2+i][col] = fmaxf(acc[i][j], 0.f);
            }
        __syncthreads();
        gemm32r2<HD, HD>(w2, b2, h, acc, tc, tr);
        __syncthreads();
        #pragma unroll
        for (int i = 0; i < 2; ++i)
            #pragma unroll
            for (int j = 0; j < 8; ++j) {
                int col = (j < 4) ? tc*4 + j : 128 + tc*4 + (j-4);
                h[tr*2+i][col] = fmaxf(acc[i][j], 0.f);
            }
        __syncthreads();
        if (tid < nrows) {
            float s = b3[0];
            for (int c = 0; c < HD; ++c) s = fmaf(h[tid][c], w3[c], s);
            exact[pl[tid].x * NPOSE + pl[tid].y] = s;
        }
        __syncthreads();
    }
}

__global__ __launch_bounds__(256)
void fixup_kernel(const float* __restrict__ x_world,
                  const float* __restrict__ inv_poses,
                  const float* __restrict__ vector,
                  float* __restrict__ out,
                  const float* __restrict__ exact)
{
    const int b = blockIdx.x * 256 + threadIdx.x;
    if (b >= BPTS) return;

    const float* pr = out + OFF_PRED + (size_t)b * NPOSE;
    float best = pr[0], best2 = 3.4e38f;
    #pragma unroll
    for (int n = 1; n < NPOSE; ++n) {
        float v = pr[n];
        if (v < best) { best2 = best; best = v; }
        else if (v < best2) { best2 = v; }
    }
    if (best2 - best >= TAU) return;

    float ebest = 3.4e38f;
    int idx = 0;
    #pragma unroll
    for (int n = 0; n < NPOSE; ++n) {
        if (pr[n] < best + TAU) {
            float v = exact[b * NPOSE + n];
            if (v < ebest) { ebest = v; idx = n; }
        }
    }
    write_point(b, idx, x_world, inv_poses, vector, out);
}

extern "C" void kernel_launch(void* const* d_in, const int* in_sizes, int n_in,
                              void* d_out, int out_size, void* d_ws, size_t ws_size,
                              hipStream_t stream)
{
    const float* x_world   = (const float*)d_in[0];
    const float* inv_poses = (const float*)d_in[1];
    const float* vector    = (const float*)d_in[2];
    const float* w0 = (const float*)d_in[3];
    const float* b0 = (const float*)d_in[4];
    const float* w1 = (const float*)d_in[5];
    const float* b1 = (const float*)d_in[6];
    const float* w2 = (const float*)d_in[7];
    const float* b2 = (const float*)d_in[8];
    const float* w3 = (const float*)d_in[9];
    const float* b3 = (const float*)d_in[10];
    float* out = (float*)d_out;

    char*  ws    = (char*)d_ws;
    f16*   wf    = (f16*)ws;
    int*   cnt   = (int*)(ws + CNT_B);
    int2*  pairs = (int2*)(ws + PAIRS_B);
    float* exact = (float*)(ws + EXACT_B);

    prep_all<<<dim3(576), dim3(256), 0, stream>>>(w0, w1, w2, wf, cnt);

    mlp_kernel<<<dim3(NPOSE * BPTS / TM), dim3(512), 0, stream>>>(
        x_world, inv_poses, b0, b1, b2, w3, b3, wf, out);
    select_kernel<<<dim3(BPTS / 256), dim3(256), 0, stream>>>(
        x_world, inv_poses, vector, out, cnt, pairs, exact);
    recompute_kernel<<<dim3(512), dim3(512), 0, stream>>>(
        x_world, inv_poses, w0, b0, w1, b1, w2, b2, w3, b3, cnt, pairs, exact);
    fixup_kernel<<<dim3(BPTS / 256), dim3(256), 0, stream>>>(
        x_world, inv_poses, vector, out, exact);
}

// Round 13
// 330.160 us; speedup vs baseline: 1.6083x; 1.1807x over previous
//
#include <hip/hip_runtime.h>
#include <cmath>

namespace {
constexpr int BPTS  = 16384;
constexpr int NPOSE = 32;
constexpr int KV    = 8;
constexpr int HD    = 256;
constexpr int TM    = 128;      // points per block (mlp)
constexpr float TAU = 0.015f;   // argmin ambiguity threshold (~3x max 2-term err)

constexpr size_t OFF_XLOCAL = 0;
constexpr size_t OFF_XLA    = (size_t)BPTS * 3;
constexpr size_t OFF_MINENC = OFF_XLA + (size_t)NPOSE * BPTS * 3;
constexpr size_t OFF_POSEQ  = OFF_MINENC + (size_t)BPTS * NPOSE;
constexpr size_t OFF_CLASS  = OFF_POSEQ + (size_t)BPTS * 16;
constexpr size_t OFF_PRED   = OFF_CLASS + (size_t)BPTS;
constexpr size_t OFF_VECQ   = OFF_PRED + (size_t)BPTS * NPOSE;

// workspace: f16 weight fragments (hi/lo), then reverify structures
constexpr size_t WS_W0H = 0;         // f16 element offsets
constexpr size_t WS_W0L = 16384;
constexpr size_t WS_W1H = 32768;
constexpr size_t WS_W1L = 98304;
constexpr size_t WS_W2H = 163840;
constexpr size_t WS_W2L = 229376;
constexpr size_t WB_END   = 589824;              // bytes
constexpr size_t CNT_B    = WB_END;
constexpr size_t PAIRS_B  = WB_END + 1024;
constexpr int    PAIR_CAP = 65536;
constexpr size_t EXACT_B  = PAIRS_B + (size_t)PAIR_CAP * 8;

// LDS layout (mlp): h buffer 64KB | feat 10KB | predp 4KB = 78KB -> 2 blocks/CU
constexpr int LDS_FEAT  = 65536;
constexpr int LDS_PREDP = 65536 + 10240;
constexpr int LDS_TOTAL = 65536 + 10240 + 4096;
}

typedef _Float16 f16;
typedef __attribute__((ext_vector_type(4))) _Float16 f16x4;
typedef __attribute__((ext_vector_type(8))) _Float16 f16x8;
typedef __attribute__((ext_vector_type(4))) float    f32x4;

#define MFMA16(a, b, c) __builtin_amdgcn_mfma_f32_16x16x32_f16((a), (b), (c), 0, 0, 0)

// ---- merged weight prep (+ cnt zero): split fp32 W[k][ch] into hi/lo f16 frags.
// idx = ((cht*KC + kc)*64 + lane)*8 + e -> W[k=kc*32+(lane>>4)*8+e][ch=cht*16+(lane&15)]
__global__ __launch_bounds__(256)
void prep_all(const float* __restrict__ w0, const float* __restrict__ w1,
              const float* __restrict__ w2, f16* __restrict__ wf, int* __restrict__ cnt)
{
    const int bid = blockIdx.x, tid = threadIdx.x;
    if (bid == 0 && tid == 0) *cnt = 0;
    if (bid < 64) {                       // w0: KC=2, 16384 frags
        int i = bid * 256 + tid;
        int e  = i & 7;
        int l  = (i >> 3) & 63;
        int kc = (i >> 9) & 1;
        int nt = i >> 10;
        int k   = kc * 32 + ((l >> 4) << 3) + e;
        int col = nt * 16 + (l & 15);
        float v = (k < 39) ? w0[k * HD + col] : 0.f;
        f16 hi = (f16)v;
        wf[WS_W0H + i] = hi;
        wf[WS_W0L + i] = (f16)(v - (float)hi);
    } else {                              // w1/w2: KC=8, 65536 frags each
        const bool is1 = bid < 320;
        const float* w = is1 ? w1 : w2;
        int i = (bid - (is1 ? 64 : 320)) * 256 + tid;
        int e  = i & 7;
        int l  = (i >> 3) & 63;
        int kc = (i >> 9) & 7;
        int nt = i >> 12;
        int k   = kc * 32 + ((l >> 4) << 3) + e;
        int col = nt * 16 + (l & 15);
        float v = w[k * HD + col];
        f16 hi = (f16)v;
        wf[(is1 ? WS_W1H : WS_W2H) + i] = hi;
        wf[(is1 ? WS_W1L : WS_W2L) + i] = (f16)(v - (float)hi);
    }
}

// swizzled byte address in the 512B full-width row: p row, cbyte 0..511
__device__ __forceinline__ int bswz(int p, int cbyte) {
    return p * 512 + (cbyte ^ ((p & 15) << 4));
}

// TM=128 full-pass: weights loaded ONCE per block (2.4GB L2 total).
// (512,4) = 128-reg total budget: acc 64 AGPR + ~55 arch; #pragma unroll 1 on kcg
// keeps live arch regs low (r9 lesson: full unroll hoists loads -> spill).
__global__ __launch_bounds__(512, 4)
void mlp_kernel(const float* __restrict__ x_world,
                const float* __restrict__ inv_poses,
                const float* __restrict__ b0, const float* __restrict__ b1,
                const float* __restrict__ b2, const float* __restrict__ w3,
                const float* __restrict__ b3, const f16* __restrict__ wf,
                float* __restrict__ out)
{
    __shared__ char lds[LDS_TOTAL];     // h[128][256] f16 | feat | predp

    f16*   feath = (f16*)(lds + LDS_FEAT);      // [128][40]
    float* predp = (float*)(lds + LDS_PREDP);   // [128][8]

    const int tid  = threadIdx.x;
    const int lane = tid & 63;
    const int wv   = tid >> 6;          // wave id 0..7 = channel group
    const int l15  = lane & 15;
    const int g    = lane >> 4;

    const int bid   = blockIdx.x;
    const int n_idx = bid >> 7;         // 128 blocks per pose
    const int bbase = (bid & 127) * TM;

    // ---- pose transform + positional encoding (4 threads per point) ----
    {
        const int p   = tid >> 2;       // 0..127
        const int sub = tid & 3;
        const int b   = bbase + p;
        const float xw0 = x_world[b*3+0], xw1 = x_world[b*3+1], xw2 = x_world[b*3+2];
        const float* P = inv_poses + n_idx * 16;
        float xl[3];
        #pragma unroll
        for (int x = 0; x < 3; ++x)
            xl[x] = P[x*4+3] + P[x*4+0]*xw0 + P[x*4+1]*xw1 + P[x*4+2]*xw2;

        auto put = [&](int c, float v) { feath[p*40 + c] = (f16)v; };
        if (sub == 0) {
            float* xla = out + OFF_XLA + ((size_t)n_idx * BPTS + b) * 3;
            #pragma unroll
            for (int x = 0; x < 3; ++x) { xla[x] = xl[x]; put(x, xl[x]); }
            put(39, 0.f);               // k-pad
        }
        #pragma unroll
        for (int t = 0; t < 3; ++t) {   // 12 sin/cos jobs, 3 per sub
            int j = sub * 3 + t;
            int o = j >> 1, fn = j & 1;
            float s = (float)(1 << o);
            #pragma unroll
            for (int x = 0; x < 3; ++x) {
                float a = xl[x] * s;
                put(3 + 6*o + 3*fn + x, fn ? cosf(a) : sinf(a));
            }
        }
    }
    __syncthreads();

    f32x4 acc[2][8];                    // [c2][pt]: 32 ch x 128 pts (64 AGPR)

    auto init_bias = [&](const float* bias) {
        #pragma unroll
        for (int c2 = 0; c2 < 2; ++c2) {
            f32x4 bv = *(const f32x4*)(bias + (wv + c2*8) * 16 + g * 4);
            #pragma unroll
            for (int pt = 0; pt < 8; ++pt) acc[c2][pt] = bv;
        }
    };
    auto packone = [&](f32x4 a) {
        return (f16x4){(f16)fmaxf(a[0],0.f), (f16)fmaxf(a[1],0.f),
                       (f16)fmaxf(a[2],0.f), (f16)fmaxf(a[3],0.f)};
    };
    auto st_all = [&]() {               // relu+pack all 16 (c2,pt) frags -> h
        #pragma unroll
        for (int c2 = 0; c2 < 2; ++c2)
            #pragma unroll
            for (int pt = 0; pt < 8; ++pt) {
                int cbyte = c2 * 256 + wv * 32 + g * 8;
                *(f16x4*)(lds + bswz(pt * 16 + l15, cbyte)) = packone(acc[c2][pt]);
            }
    };
    // hidden-layer accumulate: weights once per kcg (outer), both point halves inner
    auto hidden_accum = [&](const f16* wfh, const f16* wfl) {
        const f16* wph0 = wfh + ((size_t)(wv    ) * 4096 + lane * 8);
        const f16* wpl0 = wfl + ((size_t)(wv    ) * 4096 + lane * 8);
        const f16* wph1 = wfh + ((size_t)(wv + 8) * 4096 + lane * 8);
        const f16* wpl1 = wfl + ((size_t)(wv + 8) * 4096 + lane * 8);
        #pragma unroll 1
        for (int kcg = 0; kcg < 8; ++kcg) {
            f16x8 wh0 = *(const f16x8*)(wph0 + kcg * 512);
            f16x8 wl0 = *(const f16x8*)(wpl0 + kcg * 512);
            f16x8 wh1 = *(const f16x8*)(wph1 + kcg * 512);
            f16x8 wl1 = *(const f16x8*)(wpl1 + kcg * 512);
            #pragma unroll
            for (int half = 0; half < 2; ++half) {
                f16x8 bh[4];
                #pragma unroll
                for (int q = 0; q < 4; ++q)
                    bh[q] = *(const f16x8*)(lds +
                              bswz((half*4 + q) * 16 + l15, kcg * 64 + g * 16));
                #pragma unroll
                for (int q = 0; q < 4; ++q) {
                    acc[0][half*4+q] = MFMA16(wh0, bh[q], acc[0][half*4+q]);
                    acc[0][half*4+q] = MFMA16(wl0, bh[q], acc[0][half*4+q]);
                    acc[1][half*4+q] = MFMA16(wh1, bh[q], acc[1][half*4+q]);
                    acc[1][half*4+q] = MFMA16(wl1, bh[q], acc[1][half*4+q]);
                }
            }
        }
    };

    // ---- layer 0: feat(39, padded 64) -> acc ----
    init_bias(b0);
    {
        const f16x8 z = {};
        #pragma unroll
        for (int kc = 0; kc < 2; ++kc) {
            f16x8 wh0 = *(const f16x8*)(wf + WS_W0H + ((wv*2      + kc) * 64 + lane) * 8);
            f16x8 wl0 = *(const f16x8*)(wf + WS_W0L + ((wv*2      + kc) * 64 + lane) * 8);
            f16x8 wh1 = *(const f16x8*)(wf + WS_W0H + (((wv+8)*2  + kc) * 64 + lane) * 8);
            f16x8 wl1 = *(const f16x8*)(wf + WS_W0L + (((wv+8)*2  + kc) * 64 + lane) * 8);
            #pragma unroll
            for (int half = 0; half < 2; ++half) {
                f16x8 ah[4];
                #pragma unroll
                for (int q = 0; q < 4; ++q) {
                    int p = (half*4 + q) * 16 + l15;
                    if (kc == 0)      ah[q] = *(const f16x8*)&feath[p*40 + g*8];
                    else if (g == 0)  ah[q] = *(const f16x8*)&feath[p*40 + 32];
                    else              ah[q] = z;
                }
                #pragma unroll
                for (int q = 0; q < 4; ++q) {
                    acc[0][half*4+q] = MFMA16(wh0, ah[q], acc[0][half*4+q]);
                    acc[0][half*4+q] = MFMA16(wl0, ah[q], acc[0][half*4+q]);
                    acc[1][half*4+q] = MFMA16(wh1, ah[q], acc[1][half*4+q]);
                    acc[1][half*4+q] = MFMA16(wl1, ah[q], acc[1][half*4+q]);
                }
            }
        }
    }
    st_all();                           // h region disjoint from feath: no pre-barrier
    __syncthreads();                    // h0 complete & visible

    // ---- layer 1 ----
    init_bias(b1);
    hidden_accum(wf + WS_W1H, wf + WS_W1L);
    __syncthreads();                    // all waves done reading h0
    st_all();
    __syncthreads();                    // h1 complete & visible

    // ---- layer 2 + layer 3 fused: pred from registers, no stores ----
    init_bias(b2);
    hidden_accum(wf + WS_W2H, wf + WS_W2L);
    {
        float pp[8] = {};
        #pragma unroll
        for (int c2 = 0; c2 < 2; ++c2) {
            f32x4 wvv = *(const f32x4*)(w3 + (wv + c2*8) * 16 + g * 4);
            #pragma unroll
            for (int pt = 0; pt < 8; ++pt)
                #pragma unroll
                for (int r = 0; r < 4; ++r)
                    pp[pt] = fmaf(fmaxf(acc[c2][pt][r], 0.f), wvv[r], pp[pt]);
        }
        #pragma unroll
        for (int pt = 0; pt < 8; ++pt) {
            pp[pt] += __shfl_xor(pp[pt], 16);    // reduce over g (channel groups)
            pp[pt] += __shfl_xor(pp[pt], 32);
        }
        if (g == 0) {
            #pragma unroll
            for (int pt = 0; pt < 8; ++pt)
                predp[(pt * 16 + l15) * 8 + wv] = pp[pt];
        }
    }
    __syncthreads();
    if (tid < TM) {
        float s = b3[0];
        #pragma unroll
        for (int j = 0; j < 8; ++j) s += predp[tid * 8 + j];
        out[OFF_PRED + (size_t)(bbase + tid) * NPOSE + n_idx] = s;
    }
}

// per-point output writer (shared by select & fixup)
__device__ __forceinline__ void write_point(int b, int idx,
                                            const float* __restrict__ x_world,
                                            const float* __restrict__ inv_poses,
                                            const float* __restrict__ vector,
                                            float* __restrict__ out)
{
    float* me = out + OFF_MINENC + (size_t)b * NPOSE;
    #pragma unroll
    for (int n = 0; n < NPOSE; ++n) me[n] = (n == idx) ? 1.f : 0.f;

    const float* P = inv_poses + idx * 16;
    float* pq = out + OFF_POSEQ + (size_t)b * 16;
    #pragma unroll
    for (int m = 0; m < 16; ++m) pq[m] = P[m];

    const float xw0 = x_world[b*3+0], xw1 = x_world[b*3+1], xw2 = x_world[b*3+2];
    float* xl = out + OFF_XLOCAL + (size_t)b * 3;
    #pragma unroll
    for (int x = 0; x < 3; ++x)
        xl[x] = P[x*4+3] + P[x*4+0]*xw0 + P[x*4+1]*xw1 + P[x*4+2]*xw2;

    out[OFF_CLASS + b] = (float)idx;

    const float* vq = vector + idx * KV;
    float* ov = out + OFF_VECQ + (size_t)b * KV;
    #pragma unroll
    for (int m = 0; m < KV; ++m) ov[m] = vq[m];
}

__global__ __launch_bounds__(256)
void select_kernel(const float* __restrict__ x_world,
                   const float* __restrict__ inv_poses,
                   const float* __restrict__ vector,
                   float* __restrict__ out,
                   int* __restrict__ cnt, int2* __restrict__ pairs,
                   float* __restrict__ exact)
{
    const int b = blockIdx.x * 256 + threadIdx.x;
    if (b >= BPTS) return;

    const float* pr = out + OFF_PRED + (size_t)b * NPOSE;
    float best = pr[0], best2 = 3.4e38f;
    int idx = 0;
    #pragma unroll
    for (int n = 1; n < NPOSE; ++n) {
        float v = pr[n];
        if (v < best) { best2 = best; best = v; idx = n; }
        else if (v < best2) { best2 = v; }
    }

    if (best2 - best >= TAU) {
        write_point(b, idx, x_world, inv_poses, vector, out);
    } else {
        #pragma unroll
        for (int n = 0; n < NPOSE; ++n) {
            float v = pr[n];
            if (v < best + TAU) {
                exact[b * NPOSE + n] = v;
                int slot = atomicAdd(cnt, 1);
                if (slot < PAIR_CAP) pairs[slot] = make_int2(b, n);
            }
        }
    }
}

// ---- high-accuracy recompute for flagged pairs: 3-term split-f16 MFMA.
// 64 pairs/block, 8 waves x disjoint channel groups (weights once/block).
// Error ~ sum(wl*al) ~ 1e-5: fp32-class for argmin purposes.
__global__ __launch_bounds__(512, 4)
void recompute_kernel(const float* __restrict__ x_world,
                      const float* __restrict__ inv_poses,
                      const float* __restrict__ b0, const float* __restrict__ b1,
                      const float* __restrict__ b2, const float* __restrict__ w3,
                      const float* __restrict__ b3, const f16* __restrict__ wf,
                      const int* __restrict__ cnt, const int2* __restrict__ pairs,
                      float* __restrict__ exact)
{
    // plane_hi 32KB | plane_lo 32KB | feath 5KB | featl 5KB  (rows are 64 points)
    __shared__ char  lds[75776];
    __shared__ float predp[64][8];
    __shared__ int2  pl[64];

    f16* feath = (f16*)(lds + 65536);
    f16* featl = (f16*)(lds + 65536 + 5120);

    const int tid  = threadIdx.x;
    const int lane = tid & 63;
    const int wv   = tid >> 6;
    const int l15  = lane & 15;
    const int g    = lane >> 4;
    const int total = min(*cnt, PAIR_CAP);

    f32x4 acc[2][4];                    // [c2][q]: 32 ch x 64 rows (32 AGPR)

    auto init_bias = [&](const float* bias) {
        #pragma unroll
        for (int c2 = 0; c2 < 2; ++c2) {
            f32x4 bv = *(const f32x4*)(bias + (wv + c2*8) * 16 + g * 4);
            #pragma unroll
            for (int q = 0; q < 4; ++q) acc[c2][q] = bv;
        }
    };
    auto packpair = [&](f32x4 a, f16x4& hv, f16x4& lv) {
        float v0 = fmaxf(a[0],0.f), v1 = fmaxf(a[1],0.f);
        float v2 = fmaxf(a[2],0.f), v3 = fmaxf(a[3],0.f);
        f16 h0=(f16)v0, h1=(f16)v1, h2=(f16)v2, h3=(f16)v3;
        hv = (f16x4){h0,h1,h2,h3};
        lv = (f16x4){(f16)(v0-(float)h0),(f16)(v1-(float)h1),
                     (f16)(v2-(float)h2),(f16)(v3-(float)h3)};
    };
    auto st_all2 = [&]() {              // relu+split both planes
        #pragma unroll
        for (int c2 = 0; c2 < 2; ++c2)
            #pragma unroll
            for (int q = 0; q < 4; ++q) {
                int byte = bswz(q * 16 + l15, c2 * 256 + wv * 32 + g * 8);
                f16x4 hv, lv;
                packpair(acc[c2][q], hv, lv);
                *(f16x4*)(lds + byte)         = hv;
                *(f16x4*)(lds + 32768 + byte) = lv;
            }
    };
    auto hidden3 = [&](const f16* wfh, const f16* wfl) {
        const f16* wph0 = wfh + ((size_t)(wv    ) * 4096 + lane * 8);
        const f16* wpl0 = wfl + ((size_t)(wv    ) * 4096 + lane * 8);
        const f16* wph1 = wfh + ((size_t)(wv + 8) * 4096 + lane * 8);
        const f16* wpl1 = wfl + ((size_t)(wv + 8) * 4096 + lane * 8);
        #pragma unroll 1
        for (int kcg = 0; kcg < 8; ++kcg) {
            f16x8 wh0 = *(const f16x8*)(wph0 + kcg * 512);
            f16x8 wl0 = *(const f16x8*)(wpl0 + kcg * 512);
            f16x8 wh1 = *(const f16x8*)(wph1 + kcg * 512);
            f16x8 wl1 = *(const f16x8*)(wpl1 + kcg * 512);
            #pragma unroll
            for (int q = 0; q < 4; ++q) {
                int byte = bswz(q * 16 + l15, kcg * 64 + g * 16);
                f16x8 bh = *(const f16x8*)(lds + byte);
                f16x8 bl = *(const f16x8*)(lds + 32768 + byte);
                acc[0][q] = MFMA16(wh0, bh, acc[0][q]);
                acc[0][q] = MFMA16(wl0, bh, acc[0][q]);
                acc[0][q] = MFMA16(wh0, bl, acc[0][q]);
                acc[1][q] = MFMA16(wh1, bh, acc[1][q]);
                acc[1][q] = MFMA16(wl1, bh, acc[1][q]);
                acc[1][q] = MFMA16(wh1, bl, acc[1][q]);
            }
        }
    };

    for (int base = blockIdx.x * 64; base < total; base += gridDim.x * 64) {
        const int nrows = min(64, total - base);
        if (tid < 64) pl[tid] = (tid < nrows) ? pairs[base + tid] : make_int2(0, 0);
        __syncthreads();
        // ---- embed flagged pairs (8 threads per row), hi+lo planes ----
        {
            const int p   = tid >> 3;
            const int sub = tid & 7;
            const int2 pp = pl[p];
            const int b = pp.x;
            const float xw0 = x_world[b*3+0], xw1 = x_world[b*3+1], xw2 = x_world[b*3+2];
            const float* P = inv_poses + pp.y * 16;
            float xl[3];
            #pragma unroll
            for (int x = 0; x < 3; ++x)
                xl[x] = P[x*4+3] + P[x*4+0]*xw0 + P[x*4+1]*xw1 + P[x*4+2]*xw2;
            auto put = [&](int c, float v) {
                f16 hi = (f16)v;
                feath[p*40 + c] = hi;
                featl[p*40 + c] = (f16)(v - (float)hi);
            };
            if (sub == 0) {
                #pragma unroll
                for (int x = 0; x < 3; ++x) put(x, xl[x]);
                put(39, 0.f);
            }
            #pragma unroll
            for (int t = 0; t < 2; ++t) {
                int j = sub + 8*t;
                if (j < 12) {
                    int o = j >> 1, fn = j & 1;
                    float s = (float)(1 << o);
                    #pragma unroll
                    for (int x = 0; x < 3; ++x) {
                        float a = xl[x] * s;
                        put(3 + 6*o + 3*fn + x, fn ? cosf(a) : sinf(a));
                    }
                }
            }
        }
        __syncthreads();

        // ---- layer 0 (3-term) ----
        init_bias(b0);
        {
            const f16x8 z = {};
            #pragma unroll
            for (int kc = 0; kc < 2; ++kc) {
                f16x8 wh0 = *(const f16x8*)(wf + WS_W0H + ((wv*2     + kc)*64 + lane)*8);
                f16x8 wl0 = *(const f16x8*)(wf + WS_W0L + ((wv*2     + kc)*64 + lane)*8);
                f16x8 wh1 = *(const f16x8*)(wf + WS_W0H + (((wv+8)*2 + kc)*64 + lane)*8);
                f16x8 wl1 = *(const f16x8*)(wf + WS_W0L + (((wv+8)*2 + kc)*64 + lane)*8);
                #pragma unroll
                for (int q = 0; q < 4; ++q) {
                    int p = q * 16 + l15;
                    f16x8 ah, al;
                    if (kc == 0) {
                        ah = *(const f16x8*)&feath[p*40 + g*8];
                        al = *(const f16x8*)&featl[p*40 + g*8];
                    } else if (g == 0) {
                        ah = *(const f16x8*)&feath[p*40 + 32];
                        al = *(const f16x8*)&featl[p*40 + 32];
                    } else { ah = z; al = z; }
                    acc[0][q] = MFMA16(wh0, ah, acc[0][q]);
                    acc[0][q] = MFMA16(wl0, ah, acc[0][q]);
                    acc[0][q] = MFMA16(wh0, al, acc[0][q]);
                    acc[1][q] = MFMA16(wh1, ah, acc[1][q]);
                    acc[1][q] = MFMA16(wl1, ah, acc[1][q]);
                    acc[1][q] = MFMA16(wh1, al, acc[1][q]);
                }
            }
        }
        st_all2();                      // planes last read 2 syncs ago: safe
        __syncthreads();

        // ---- layer 1 ----
        init_bias(b1);
        hidden3(wf + WS_W1H, wf + WS_W1L);
        __syncthreads();
        st_all2();
        __syncthreads();

        // ---- layer 2 + layer 3 ----
        init_bias(b2);
        hidden3(wf + WS_W2H, wf + WS_W2L);
        {
            float pp4[4] = {};
            #pragma unroll
            for (int c2 = 0; c2 < 2; ++c2) {
                f32x4 wvv = *(const f32x4*)(w3 + (wv + c2*8) * 16 + g * 4);
                #pragma unroll
                for (int q = 0; q < 4; ++q)
                    #pragma unroll
                    for (int r = 0; r < 4; ++r)
                        pp4[q] = fmaf(fmaxf(acc[c2][q][r], 0.f), wvv[r], pp4[q]);
            }
            #pragma unroll
            for (int q = 0; q < 4; ++q) {
                pp4[q] += __shfl_xor(pp4[q], 16);
                pp4[q] += __shfl_xor(pp4[q], 32);
            }
            if (g == 0) {
                #pragma unroll
                for (int q = 0; q < 4; ++q)
                    predp[q * 16 + l15][wv] = pp4[q];
            }
        }
        __syncthreads();
        if (tid < nrows) {
            float s = b3[0];
            #pragma unroll
            for (int j = 0; j < 8; ++j) s += predp[tid][j];
            exact[pl[tid].x * NPOSE + pl[tid].y] = s;
        }
        __syncthreads();                // protect predp/pl before next chunk
    }
}

__global__ __launch_bounds__(256)
void fixup_kernel(const float* __restrict__ x_world,
                  const float* __restrict__ inv_poses,
                  const float* __restrict__ vector,
                  float* __restrict__ out,
                  const float* __restrict__ exact)
{
    const int b = blockIdx.x * 256 + threadIdx.x;
    if (b >= BPTS) return;

    const float* pr = out + OFF_PRED + (size_t)b * NPOSE;
    float best = pr[0], best2 = 3.4e38f;
    #pragma unroll
    for (int n = 1; n < NPOSE; ++n) {
        float v = pr[n];
        if (v < best) { best2 = best; best = v; }
        else if (v < best2) { best2 = v; }
    }
    if (best2 - best >= TAU) return;

    float ebest = 3.4e38f;
    int idx = 0;
    #pragma unroll
    for (int n = 0; n < NPOSE; ++n) {
        if (pr[n] < best + TAU) {
            float v = exact[b * NPOSE + n];
            if (v < ebest) { ebest = v; idx = n; }
        }
    }
    write_point(b, idx, x_world, inv_poses, vector, out);
}

extern "C" void kernel_launch(void* const* d_in, const int* in_sizes, int n_in,
                              void* d_out, int out_size, void* d_ws, size_t ws_size,
                              hipStream_t stream)
{
    const float* x_world   = (const float*)d_in[0];
    const float* inv_poses = (const float*)d_in[1];
    const float* vector    = (const float*)d_in[2];
    const float* w0 = (const float*)d_in[3];
    const float* b0 = (const float*)d_in[4];
    const float* w1 = (const float*)d_in[5];
    const float* b1 = (const float*)d_in[6];
    const float* w2 = (const float*)d_in[7];
    const float* b2 = (const float*)d_in[8];
    const float* w3 = (const float*)d_in[9];
    const float* b3 = (const float*)d_in[10];
    float* out = (float*)d_out;

    char*  ws    = (char*)d_ws;
    f16*   wf    = (f16*)ws;
    int*   cnt   = (int*)(ws + CNT_B);
    int2*  pairs = (int2*)(ws + PAIRS_B);
    float* exact = (float*)(ws + EXACT_B);

    prep_all<<<dim3(576), dim3(256), 0, stream>>>(w0, w1, w2, wf, cnt);

    mlp_kernel<<<dim3(NPOSE * BPTS / TM), dim3(512), 0, stream>>>(
        x_world, inv_poses, b0, b1, b2, w3, b3, wf, out);
    select_kernel<<<dim3(BPTS / 256), dim3(256), 0, stream>>>(
        x_world, inv_poses, vector, out, cnt, pairs, exact);
    recompute_kernel<<<dim3(512), dim3(512), 0, stream>>>(
        x_world, inv_poses, b0, b1, b2, w3, b3, wf, cnt, pairs, exact);
    fixup_kernel<<<dim3(BPTS / 256), dim3(256), 0, stream>>>(
        x_world, inv_poses, vector, out, exact);
}

// Round 14
// 287.473 us; speedup vs baseline: 1.8471x; 1.1485x over previous
//
#include <hip/hip_runtime.h>
#include <cmath>

namespace {
constexpr int BPTS  = 16384;
constexpr int NPOSE = 32;
constexpr int KV    = 8;
constexpr int HD    = 256;
constexpr int TM    = 128;      // points per block (mlp)
constexpr float TAU = 0.04f;    // argmin ambiguity threshold (~3.6x max 1-term err)

constexpr size_t OFF_XLOCAL = 0;
constexpr size_t OFF_XLA    = (size_t)BPTS * 3;
constexpr size_t OFF_MINENC = OFF_XLA + (size_t)NPOSE * BPTS * 3;
constexpr size_t OFF_POSEQ  = OFF_MINENC + (size_t)BPTS * NPOSE;
constexpr size_t OFF_CLASS  = OFF_POSEQ + (size_t)BPTS * 16;
constexpr size_t OFF_PRED   = OFF_CLASS + (size_t)BPTS;
constexpr size_t OFF_VECQ   = OFF_PRED + (size_t)BPTS * NPOSE;

// workspace: f16 weight fragments (hi/lo), then reverify structures
constexpr size_t WS_W0H = 0;         // f16 element offsets
constexpr size_t WS_W0L = 16384;
constexpr size_t WS_W1H = 32768;
constexpr size_t WS_W1L = 98304;
constexpr size_t WS_W2H = 163840;
constexpr size_t WS_W2L = 229376;
constexpr size_t WB_END   = 589824;              // bytes
constexpr size_t CNT_B    = WB_END;
constexpr size_t PAIRS_B  = WB_END + 1024;
constexpr int    PAIR_CAP = 65536;
constexpr size_t EXACT_B  = PAIRS_B + (size_t)PAIR_CAP * 8;

// LDS layout (mlp): h buffer 64KB | feat 10KB | predp 4KB = 78KB -> 2 blocks/CU
constexpr int LDS_FEAT  = 65536;
constexpr int LDS_PREDP = 65536 + 10240;
constexpr int LDS_TOTAL = 65536 + 10240 + 4096;
}

typedef _Float16 f16;
typedef __attribute__((ext_vector_type(4))) _Float16 f16x4;
typedef __attribute__((ext_vector_type(8))) _Float16 f16x8;
typedef __attribute__((ext_vector_type(4))) float    f32x4;

#define MFMA16(a, b, c) __builtin_amdgcn_mfma_f32_16x16x32_f16((a), (b), (c), 0, 0, 0)

// ---- merged weight prep (+ cnt zero): split fp32 W[k][ch] into hi/lo f16 frags.
// idx = ((cht*KC + kc)*64 + lane)*8 + e -> W[k=kc*32+(lane>>4)*8+e][ch=cht*16+(lane&15)]
// Main mlp uses hi plane only (1-term); 3-term recompute uses both.
__global__ __launch_bounds__(256)
void prep_all(const float* __restrict__ w0, const float* __restrict__ w1,
              const float* __restrict__ w2, f16* __restrict__ wf, int* __restrict__ cnt)
{
    const int bid = blockIdx.x, tid = threadIdx.x;
    if (bid == 0 && tid == 0) *cnt = 0;
    if (bid < 64) {                       // w0: KC=2, 16384 frags
        int i = bid * 256 + tid;
        int e  = i & 7;
        int l  = (i >> 3) & 63;
        int kc = (i >> 9) & 1;
        int nt = i >> 10;
        int k   = kc * 32 + ((l >> 4) << 3) + e;
        int col = nt * 16 + (l & 15);
        float v = (k < 39) ? w0[k * HD + col] : 0.f;
        f16 hi = (f16)v;
        wf[WS_W0H + i] = hi;
        wf[WS_W0L + i] = (f16)(v - (float)hi);
    } else {                              // w1/w2: KC=8, 65536 frags each
        const bool is1 = bid < 320;
        const float* w = is1 ? w1 : w2;
        int i = (bid - (is1 ? 64 : 320)) * 256 + tid;
        int e  = i & 7;
        int l  = (i >> 3) & 63;
        int kc = (i >> 9) & 7;
        int nt = i >> 12;
        int k   = kc * 32 + ((l >> 4) << 3) + e;
        int col = nt * 16 + (l & 15);
        float v = w[k * HD + col];
        f16 hi = (f16)v;
        wf[(is1 ? WS_W1H : WS_W2H) + i] = hi;
        wf[(is1 ? WS_W1L : WS_W2L) + i] = (f16)(v - (float)hi);
    }
}

// swizzled byte address in the 512B full-width row: p row, cbyte 0..511
__device__ __forceinline__ int bswz(int p, int cbyte) {
    return p * 512 + (cbyte ^ ((p & 15) << 4));
}

// TM=128 full-pass, 1-TERM (wh only): MFMA floor 75us. (512,4) = 128-reg budget:
// acc 64 AGPR + ~50 arch; #pragma unroll 1 on kcg keeps live arch regs low.
__global__ __launch_bounds__(512, 4)
void mlp_kernel(const float* __restrict__ x_world,
                const float* __restrict__ inv_poses,
                const float* __restrict__ b0, const float* __restrict__ b1,
                const float* __restrict__ b2, const float* __restrict__ w3,
                const float* __restrict__ b3, const f16* __restrict__ wf,
                float* __restrict__ out)
{
    __shared__ char lds[LDS_TOTAL];     // h[128][256] f16 | feat | predp

    f16*   feath = (f16*)(lds + LDS_FEAT);      // [128][40]
    float* predp = (float*)(lds + LDS_PREDP);   // [128][8]

    const int tid  = threadIdx.x;
    const int lane = tid & 63;
    const int wv   = tid >> 6;          // wave id 0..7 = channel group
    const int l15  = lane & 15;
    const int g    = lane >> 4;

    const int bid   = blockIdx.x;
    const int n_idx = bid >> 7;         // 128 blocks per pose
    const int bbase = (bid & 127) * TM;

    // ---- pose transform + positional encoding (4 threads per point) ----
    {
        const int p   = tid >> 2;       // 0..127
        const int sub = tid & 3;
        const int b   = bbase + p;
        const float xw0 = x_world[b*3+0], xw1 = x_world[b*3+1], xw2 = x_world[b*3+2];
        const float* P = inv_poses + n_idx * 16;
        float xl[3];
        #pragma unroll
        for (int x = 0; x < 3; ++x)
            xl[x] = P[x*4+3] + P[x*4+0]*xw0 + P[x*4+1]*xw1 + P[x*4+2]*xw2;

        auto put = [&](int c, float v) { feath[p*40 + c] = (f16)v; };
        if (sub == 0) {
            float* xla = out + OFF_XLA + ((size_t)n_idx * BPTS + b) * 3;
            #pragma unroll
            for (int x = 0; x < 3; ++x) { xla[x] = xl[x]; put(x, xl[x]); }
            put(39, 0.f);               // k-pad
        }
        #pragma unroll
        for (int t = 0; t < 3; ++t) {   // 12 sin/cos jobs, 3 per sub
            int j = sub * 3 + t;
            int o = j >> 1, fn = j & 1;
            float s = (float)(1 << o);
            #pragma unroll
            for (int x = 0; x < 3; ++x) {
                float a = xl[x] * s;
                put(3 + 6*o + 3*fn + x, fn ? cosf(a) : sinf(a));
            }
        }
    }
    __syncthreads();

    f32x4 acc[2][8];                    // [c2][pt]: 32 ch x 128 pts (64 AGPR)

    auto init_bias = [&](const float* bias) {
        #pragma unroll
        for (int c2 = 0; c2 < 2; ++c2) {
            f32x4 bv = *(const f32x4*)(bias + (wv + c2*8) * 16 + g * 4);
            #pragma unroll
            for (int pt = 0; pt < 8; ++pt) acc[c2][pt] = bv;
        }
    };
    auto packone = [&](f32x4 a) {
        return (f16x4){(f16)fmaxf(a[0],0.f), (f16)fmaxf(a[1],0.f),
                       (f16)fmaxf(a[2],0.f), (f16)fmaxf(a[3],0.f)};
    };
    auto st_all = [&]() {               // relu+pack all 16 (c2,pt) frags -> h
        #pragma unroll
        for (int c2 = 0; c2 < 2; ++c2)
            #pragma unroll
            for (int pt = 0; pt < 8; ++pt) {
                int cbyte = c2 * 256 + wv * 32 + g * 8;
                *(f16x4*)(lds + bswz(pt * 16 + l15, cbyte)) = packone(acc[c2][pt]);
            }
    };
    // hidden-layer accumulate, 1-term: hi weights only, once per kcg (outer)
    auto hidden_accum = [&](const f16* wfh) {
        const f16* wph0 = wfh + ((size_t)(wv    ) * 4096 + lane * 8);
        const f16* wph1 = wfh + ((size_t)(wv + 8) * 4096 + lane * 8);
        #pragma unroll 1
        for (int kcg = 0; kcg < 8; ++kcg) {
            f16x8 wh0 = *(const f16x8*)(wph0 + kcg * 512);
            f16x8 wh1 = *(const f16x8*)(wph1 + kcg * 512);
            #pragma unroll
            for (int half = 0; half < 2; ++half) {
                f16x8 bh[4];
                #pragma unroll
                for (int q = 0; q < 4; ++q)
                    bh[q] = *(const f16x8*)(lds +
                              bswz((half*4 + q) * 16 + l15, kcg * 64 + g * 16));
                #pragma unroll
                for (int q = 0; q < 4; ++q) {
                    acc[0][half*4+q] = MFMA16(wh0, bh[q], acc[0][half*4+q]);
                    acc[1][half*4+q] = MFMA16(wh1, bh[q], acc[1][half*4+q]);
                }
            }
        }
    };

    // ---- layer 0: feat(39, padded 64) -> acc, 1-term ----
    init_bias(b0);
    {
        const f16x8 z = {};
        #pragma unroll
        for (int kc = 0; kc < 2; ++kc) {
            f16x8 wh0 = *(const f16x8*)(wf + WS_W0H + ((wv*2      + kc) * 64 + lane) * 8);
            f16x8 wh1 = *(const f16x8*)(wf + WS_W0H + (((wv+8)*2  + kc) * 64 + lane) * 8);
            #pragma unroll
            for (int half = 0; half < 2; ++half) {
                f16x8 ah[4];
                #pragma unroll
                for (int q = 0; q < 4; ++q) {
                    int p = (half*4 + q) * 16 + l15;
                    if (kc == 0)      ah[q] = *(const f16x8*)&feath[p*40 + g*8];
                    else if (g == 0)  ah[q] = *(const f16x8*)&feath[p*40 + 32];
                    else              ah[q] = z;
                }
                #pragma unroll
                for (int q = 0; q < 4; ++q) {
                    acc[0][half*4+q] = MFMA16(wh0, ah[q], acc[0][half*4+q]);
                    acc[1][half*4+q] = MFMA16(wh1, ah[q], acc[1][half*4+q]);
                }
            }
        }
    }
    st_all();                           // h region disjoint from feath: no pre-barrier
    __syncthreads();                    // h0 complete & visible

    // ---- layer 1 ----
    init_bias(b1);
    hidden_accum(wf + WS_W1H);
    __syncthreads();                    // all waves done reading h0
    st_all();
    __syncthreads();                    // h1 complete & visible

    // ---- layer 2 + layer 3 fused: pred from registers, no stores ----
    init_bias(b2);
    hidden_accum(wf + WS_W2H);
    {
        float pp[8] = {};
        #pragma unroll
        for (int c2 = 0; c2 < 2; ++c2) {
            f32x4 wvv = *(const f32x4*)(w3 + (wv + c2*8) * 16 + g * 4);
            #pragma unroll
            for (int pt = 0; pt < 8; ++pt)
                #pragma unroll
                for (int r = 0; r < 4; ++r)
                    pp[pt] = fmaf(fmaxf(acc[c2][pt][r], 0.f), wvv[r], pp[pt]);
        }
        #pragma unroll
        for (int pt = 0; pt < 8; ++pt) {
            pp[pt] += __shfl_xor(pp[pt], 16);    // reduce over g (channel groups)
            pp[pt] += __shfl_xor(pp[pt], 32);
        }
        if (g == 0) {
            #pragma unroll
            for (int pt = 0; pt < 8; ++pt)
                predp[(pt * 16 + l15) * 8 + wv] = pp[pt];
        }
    }
    __syncthreads();
    if (tid < TM) {
        float s = b3[0];
        #pragma unroll
        for (int j = 0; j < 8; ++j) s += predp[tid * 8 + j];
        out[OFF_PRED + (size_t)(bbase + tid) * NPOSE + n_idx] = s;
    }
}

// per-point output writer (shared by select & fixup)
__device__ __forceinline__ void write_point(int b, int idx,
                                            const float* __restrict__ x_world,
                                            const float* __restrict__ inv_poses,
                                            const float* __restrict__ vector,
                                            float* __restrict__ out)
{
    float* me = out + OFF_MINENC + (size_t)b * NPOSE;
    #pragma unroll
    for (int n = 0; n < NPOSE; ++n) me[n] = (n == idx) ? 1.f : 0.f;

    const float* P = inv_poses + idx * 16;
    float* pq = out + OFF_POSEQ + (size_t)b * 16;
    #pragma unroll
    for (int m = 0; m < 16; ++m) pq[m] = P[m];

    const float xw0 = x_world[b*3+0], xw1 = x_world[b*3+1], xw2 = x_world[b*3+2];
    float* xl = out + OFF_XLOCAL + (size_t)b * 3;
    #pragma unroll
    for (int x = 0; x < 3; ++x)
        xl[x] = P[x*4+3] + P[x*4+0]*xw0 + P[x*4+1]*xw1 + P[x*4+2]*xw2;

    out[OFF_CLASS + b] = (float)idx;

    const float* vq = vector + idx * KV;
    float* ov = out + OFF_VECQ + (size_t)b * KV;
    #pragma unroll
    for (int m = 0; m < KV; ++m) ov[m] = vq[m];
}

__global__ __launch_bounds__(256)
void select_kernel(const float* __restrict__ x_world,
                   const float* __restrict__ inv_poses,
                   const float* __restrict__ vector,
                   float* __restrict__ out,
                   int* __restrict__ cnt, int2* __restrict__ pairs,
                   float* __restrict__ exact)
{
    const int b = blockIdx.x * 256 + threadIdx.x;
    if (b >= BPTS) return;

    const float* pr = out + OFF_PRED + (size_t)b * NPOSE;
    float best = pr[0], best2 = 3.4e38f;
    int idx = 0;
    #pragma unroll
    for (int n = 1; n < NPOSE; ++n) {
        float v = pr[n];
        if (v < best) { best2 = best; best = v; idx = n; }
        else if (v < best2) { best2 = v; }
    }

    if (best2 - best >= TAU) {
        write_point(b, idx, x_world, inv_poses, vector, out);
    } else {
        #pragma unroll
        for (int n = 0; n < NPOSE; ++n) {
            float v = pr[n];
            if (v < best + TAU) {
                exact[b * NPOSE + n] = v;
                int slot = atomicAdd(cnt, 1);
                if (slot < PAIR_CAP) pairs[slot] = make_int2(b, n);
            }
        }
    }
}

// ---- high-accuracy recompute for flagged pairs: 3-term split-f16 MFMA.
// 64 pairs/block, 8 waves x disjoint channel groups (weights once/block).
// Error ~ sum(wl*al) ~ 1e-5: fp32-class for argmin purposes.
__global__ __launch_bounds__(512, 4)
void recompute_kernel(const float* __restrict__ x_world,
                      const float* __restrict__ inv_poses,
                      const float* __restrict__ b0, const float* __restrict__ b1,
                      const float* __restrict__ b2, const float* __restrict__ w3,
                      const float* __restrict__ b3, const f16* __restrict__ wf,
                      const int* __restrict__ cnt, const int2* __restrict__ pairs,
                      float* __restrict__ exact)
{
    // plane_hi 32KB | plane_lo 32KB | feath 5KB | featl 5KB  (rows are 64 points)
    __shared__ char  lds[75776];
    __shared__ float predp[64][8];
    __shared__ int2  pl[64];

    f16* feath = (f16*)(lds + 65536);
    f16* featl = (f16*)(lds + 65536 + 5120);

    const int tid  = threadIdx.x;
    const int lane = tid & 63;
    const int wv   = tid >> 6;
    const int l15  = lane & 15;
    const int g    = lane >> 4;
    const int total = min(*cnt, PAIR_CAP);

    f32x4 acc[2][4];                    // [c2][q]: 32 ch x 64 rows (32 AGPR)

    auto init_bias = [&](const float* bias) {
        #pragma unroll
        for (int c2 = 0; c2 < 2; ++c2) {
            f32x4 bv = *(const f32x4*)(bias + (wv + c2*8) * 16 + g * 4);
            #pragma unroll
            for (int q = 0; q < 4; ++q) acc[c2][q] = bv;
        }
    };
    auto packpair = [&](f32x4 a, f16x4& hv, f16x4& lv) {
        float v0 = fmaxf(a[0],0.f), v1 = fmaxf(a[1],0.f);
        float v2 = fmaxf(a[2],0.f), v3 = fmaxf(a[3],0.f);
        f16 h0=(f16)v0, h1=(f16)v1, h2=(f16)v2, h3=(f16)v3;
        hv = (f16x4){h0,h1,h2,h3};
        lv = (f16x4){(f16)(v0-(float)h0),(f16)(v1-(float)h1),
                     (f16)(v2-(float)h2),(f16)(v3-(float)h3)};
    };
    auto st_all2 = [&]() {              // relu+split both planes
        #pragma unroll
        for (int c2 = 0; c2 < 2; ++c2)
            #pragma unroll
            for (int q = 0; q < 4; ++q) {
                int byte = bswz(q * 16 + l15, c2 * 256 + wv * 32 + g * 8);
                f16x4 hv, lv;
                packpair(acc[c2][q], hv, lv);
                *(f16x4*)(lds + byte)         = hv;
                *(f16x4*)(lds + 32768 + byte) = lv;
            }
    };
    auto hidden3 = [&](const f16* wfh, const f16* wfl) {
        const f16* wph0 = wfh + ((size_t)(wv    ) * 4096 + lane * 8);
        const f16* wpl0 = wfl + ((size_t)(wv    ) * 4096 + lane * 8);
        const f16* wph1 = wfh + ((size_t)(wv + 8) * 4096 + lane * 8);
        const f16* wpl1 = wfl + ((size_t)(wv + 8) * 4096 + lane * 8);
        #pragma unroll 1
        for (int kcg = 0; kcg < 8; ++kcg) {
            f16x8 wh0 = *(const f16x8*)(wph0 + kcg * 512);
            f16x8 wl0 = *(const f16x8*)(wpl0 + kcg * 512);
            f16x8 wh1 = *(const f16x8*)(wph1 + kcg * 512);
            f16x8 wl1 = *(const f16x8*)(wpl1 + kcg * 512);
            #pragma unroll
            for (int q = 0; q < 4; ++q) {
                int byte = bswz(q * 16 + l15, kcg * 64 + g * 16);
                f16x8 bh = *(const f16x8*)(lds + byte);
                f16x8 bl = *(const f16x8*)(lds + 32768 + byte);
                acc[0][q] = MFMA16(wh0, bh, acc[0][q]);
                acc[0][q] = MFMA16(wl0, bh, acc[0][q]);
                acc[0][q] = MFMA16(wh0, bl, acc[0][q]);
                acc[1][q] = MFMA16(wh1, bh, acc[1][q]);
                acc[1][q] = MFMA16(wl1, bh, acc[1][q]);
                acc[1][q] = MFMA16(wh1, bl, acc[1][q]);
            }
        }
    };

    for (int base = blockIdx.x * 64; base < total; base += gridDim.x * 64) {
        const int nrows = min(64, total - base);
        if (tid < 64) pl[tid] = (tid < nrows) ? pairs[base + tid] : make_int2(0, 0);
        __syncthreads();
        // ---- embed flagged pairs (8 threads per row), hi+lo planes ----
        {
            const int p   = tid >> 3;
            const int sub = tid & 7;
            const int2 pp = pl[p];
            const int b = pp.x;
            const float xw0 = x_world[b*3+0], xw1 = x_world[b*3+1], xw2 = x_world[b*3+2];
            const float* P = inv_poses + pp.y * 16;
            float xl[3];
            #pragma unroll
            for (int x = 0; x < 3; ++x)
                xl[x] = P[x*4+3] + P[x*4+0]*xw0 + P[x*4+1]*xw1 + P[x*4+2]*xw2;
            auto put = [&](int c, float v) {
                f16 hi = (f16)v;
                feath[p*40 + c] = hi;
                featl[p*40 + c] = (f16)(v - (float)hi);
            };
            if (sub == 0) {
                #pragma unroll
                for (int x = 0; x < 3; ++x) put(x, xl[x]);
                put(39, 0.f);
            }
            #pragma unroll
            for (int t = 0; t < 2; ++t) {
                int j = sub + 8*t;
                if (j < 12) {
                    int o = j >> 1, fn = j & 1;
                    float s = (float)(1 << o);
                    #pragma unroll
                    for (int x = 0; x < 3; ++x) {
                        float a = xl[x] * s;
                        put(3 + 6*o + 3*fn + x, fn ? cosf(a) : sinf(a));
                    }
                }
            }
        }
        __syncthreads();

        // ---- layer 0 (3-term) ----
        init_bias(b0);
        {
            const f16x8 z = {};
            #pragma unroll
            for (int kc = 0; kc < 2; ++kc) {
                f16x8 wh0 = *(const f16x8*)(wf + WS_W0H + ((wv*2     + kc)*64 + lane)*8);
                f16x8 wl0 = *(const f16x8*)(wf + WS_W0L + ((wv*2     + kc)*64 + lane)*8);
                f16x8 wh1 = *(const f16x8*)(wf + WS_W0H + (((wv+8)*2 + kc)*64 + lane)*8);
                f16x8 wl1 = *(const f16x8*)(wf + WS_W0L + (((wv+8)*2 + kc)*64 + lane)*8);
                #pragma unroll
                for (int q = 0; q < 4; ++q) {
                    int p = q * 16 + l15;
                    f16x8 ah, al;
                    if (kc == 0) {
                        ah = *(const f16x8*)&feath[p*40 + g*8];
                        al = *(const f16x8*)&featl[p*40 + g*8];
                    } else if (g == 0) {
                        ah = *(const f16x8*)&feath[p*40 + 32];
                        al = *(const f16x8*)&featl[p*40 + 32];
                    } else { ah = z; al = z; }
                    acc[0][q] = MFMA16(wh0, ah, acc[0][q]);
                    acc[0][q] = MFMA16(wl0, ah, acc[0][q]);
                    acc[0][q] = MFMA16(wh0, al, acc[0][q]);
                    acc[1][q] = MFMA16(wh1, ah, acc[1][q]);
                    acc[1][q] = MFMA16(wl1, ah, acc[1][q]);
                    acc[1][q] = MFMA16(wh1, al, acc[1][q]);
                }
            }
        }
        st_all2();                      // planes last read 2 syncs ago: safe
        __syncthreads();

        // ---- layer 1 ----
        init_bias(b1);
        hidden3(wf + WS_W1H, wf + WS_W1L);
        __syncthreads();
        st_all2();
        __syncthreads();

        // ---- layer 2 + layer 3 ----
        init_bias(b2);
        hidden3(wf + WS_W2H, wf + WS_W2L);
        {
            float pp4[4] = {};
            #pragma unroll
            for (int c2 = 0; c2 < 2; ++c2) {
                f32x4 wvv = *(const f32x4*)(w3 + (wv + c2*8) * 16 + g * 4);
                #pragma unroll
                for (int q = 0; q < 4; ++q)
                    #pragma unroll
                    for (int r = 0; r < 4; ++r)
                        pp4[q] = fmaf(fmaxf(acc[c2][q][r], 0.f), wvv[r], pp4[q]);
            }
            #pragma unroll
            for (int q = 0; q < 4; ++q) {
                pp4[q] += __shfl_xor(pp4[q], 16);
                pp4[q] += __shfl_xor(pp4[q], 32);
            }
            if (g == 0) {
                #pragma unroll
                for (int q = 0; q < 4; ++q)
                    predp[q * 16 + l15][wv] = pp4[q];
            }
        }
        __syncthreads();
        if (tid < nrows) {
            float s = b3[0];
            #pragma unroll
            for (int j = 0; j < 8; ++j) s += predp[tid][j];
            exact[pl[tid].x * NPOSE + pl[tid].y] = s;
        }
        __syncthreads();                // protect predp/pl before next chunk
    }
}

__global__ __launch_bounds__(256)
void fixup_kernel(const float* __restrict__ x_world,
                  const float* __restrict__ inv_poses,
                  const float* __restrict__ vector,
                  float* __restrict__ out,
                  const float* __restrict__ exact)
{
    const int b = blockIdx.x * 256 + threadIdx.x;
    if (b >= BPTS) return;

    const float* pr = out + OFF_PRED + (size_t)b * NPOSE;
    float best = pr[0], best2 = 3.4e38f;
    #pragma unroll
    for (int n = 1; n < NPOSE; ++n) {
        float v = pr[n];
        if (v < best) { best2 = best; best = v; }
        else if (v < best2) { best2 = v; }
    }
    if (best2 - best >= TAU) return;

    float ebest = 3.4e38f;
    int idx = 0;
    #pragma unroll
    for (int n = 0; n < NPOSE; ++n) {
        if (pr[n] < best + TAU) {
            float v = exact[b * NPOSE + n];
            if (v < ebest) { ebest = v; idx = n; }
        }
    }
    write_point(b, idx, x_world, inv_poses, vector, out);
}

extern "C" void kernel_launch(void* const* d_in, const int* in_sizes, int n_in,
                              void* d_out, int out_size, void* d_ws, size_t ws_size,
                              hipStream_t stream)
{
    const float* x_world   = (const float*)d_in[0];
    const float* inv_poses = (const float*)d_in[1];
    const float* vector    = (const float*)d_in[2];
    const float* w0 = (const float*)d_in[3];
    const float* b0 = (const float*)d_in[4];
    const float* w1 = (const float*)d_in[5];
    const float* b1 = (const float*)d_in[6];
    const float* w2 = (const float*)d_in[7];
    const float* b2 = (const float*)d_in[8];
    const float* w3 = (const float*)d_in[9];
    const float* b3 = (const float*)d_in[10];
    float* out = (float*)d_out;

    char*  ws    = (char*)d_ws;
    f16*   wf    = (f16*)ws;
    int*   cnt   = (int*)(ws + CNT_B);
    int2*  pairs = (int2*)(ws + PAIRS_B);
    float* exact = (float*)(ws + EXACT_B);

    prep_all<<<dim3(576), dim3(256), 0, stream>>>(w0, w1, w2, wf, cnt);

    mlp_kernel<<<dim3(NPOSE * BPTS / TM), dim3(512), 0, stream>>>(
        x_world, inv_poses, b0, b1, b2, w3, b3, wf, out);
    select_kernel<<<dim3(BPTS / 256), dim3(256), 0, stream>>>(
        x_world, inv_poses, vector, out, cnt, pairs, exact);
    recompute_kernel<<<dim3(512), dim3(512), 0, stream>>>(
        x_world, inv_poses, b0, b1, b2, w3, b3, wf, cnt, pairs, exact);
    fixup_kernel<<<dim3(BPTS / 256), dim3(256), 0, stream>>>(
        x_world, inv_poses, vector, out, exact);
}